// Round 1
// baseline (1323.988 us; speedup 1.0000x reference)
//
#include <hip/hip_runtime.h>
#include <math.h>

namespace {

constexpr int LN    = 2048;
constexpr int DM    = 256;
constexpr int NH    = 16;
constexpr int CONVD = 1280;
constexpr int DPROJ = 2320;
constexpr int NCH   = 8;

// workspace layout (in floats)
constexpr size_t F_STATS = 0;                 // 4: mu0,rstd0,mu1,rstd1
constexpr size_t F_PART  = 4;                 // 256: partial sums
constexpr size_t F_T     = 260;               // normalized transposed input (B,L,256)
constexpr size_t SZ_T    = 2ull * 2048 * 256; // 1048576
constexpr size_t F_YF    = F_T + SZ_T;
constexpr size_t F_YB    = F_YF + SZ_T;
constexpr size_t F_SCR   = F_YB + SZ_T;       // per-direction scratch (reused)

constexpr size_t S_ZX  = 0;                   // (B*L, 2320)
constexpr size_t SZ_ZX = 2ull * 2048 * 2320;  // 9502720
constexpr size_t S_XP  = S_ZX + SZ_ZX;        // (B*L, 1280) post-conv
constexpr size_t SZ_XP = 2ull * 2048 * 1280;  // 5242880
constexpr size_t S_DT  = S_XP + SZ_XP;        // (B*L,16)
constexpr size_t S_A   = S_DT + 65536;        // (B*L,16)
constexpr size_t S_ACS = S_A + 65536;         // (B*NCH*NH,256)
constexpr size_t S_TT  = S_ACS + 65536;       // (B*NCH*NH)
constexpr size_t S_CB  = S_TT + 256;          // (B*NCH,256,256)
constexpr size_t S_ST  = S_CB + 1048576;      // (B*NCH*NH, 64*128)
constexpr size_t S_SIN = S_ST + 2097152;      // same
constexpr size_t S_YHP = S_SIN + 2097152;     // (B*L,1024)
// r/pr overlay scratch after both directions:
constexpr size_t S_R  = S_ZX;                 // (B*L,512) = 2097152
constexpr size_t S_PR = S_ZX + 2097152;       // (B*L,256) = 1048576

__device__ __forceinline__ float silu(float v) { return v / (1.f + expf(-v)); }

// ---------------- groupnorm stats ----------------
__global__ __launch_bounds__(256) void stats_partial_k(const float* __restrict__ x,
                                                       float* __restrict__ part) {
  int b = blockIdx.y, seg = blockIdx.x;
  const float4* base = (const float4*)(x + (size_t)b * 524288 + (size_t)seg * 8192);
  float s = 0.f, q = 0.f;
#pragma unroll
  for (int i = 0; i < 8; i++) {
    float4 v = base[threadIdx.x + i * 256];
    s += v.x + v.y + v.z + v.w;
    q += v.x * v.x + v.y * v.y + v.z * v.z + v.w * v.w;
  }
  for (int o = 32; o > 0; o >>= 1) { s += __shfl_down(s, o); q += __shfl_down(q, o); }
  __shared__ float ss[4], qq[4];
  int wid = threadIdx.x >> 6;
  if ((threadIdx.x & 63) == 0) { ss[wid] = s; qq[wid] = q; }
  __syncthreads();
  if (threadIdx.x == 0) {
    part[(b * 64 + seg) * 2]     = ss[0] + ss[1] + ss[2] + ss[3];
    part[(b * 64 + seg) * 2 + 1] = qq[0] + qq[1] + qq[2] + qq[3];
  }
}

__global__ __launch_bounds__(64) void stats_final_k(const float* __restrict__ part,
                                                    float* __restrict__ stats) {
  int b = blockIdx.x;
  float s = part[(b * 64 + threadIdx.x) * 2];
  float q = part[(b * 64 + threadIdx.x) * 2 + 1];
  for (int o = 32; o > 0; o >>= 1) { s += __shfl_down(s, o); q += __shfl_down(q, o); }
  if (threadIdx.x == 0) {
    float mu  = s / 524288.f;
    float var = q / 524288.f - mu * mu;
    stats[b * 2]     = mu;
    stats[b * 2 + 1] = rsqrtf(var + 1.1920929e-07f);
  }
}

// ---------------- normalize + transpose ----------------
__global__ __launch_bounds__(256) void norm_t_k(const float* __restrict__ x,
                                                const float* __restrict__ gw,
                                                const float* __restrict__ gb,
                                                const float* __restrict__ stats,
                                                float* __restrict__ t) {
  int row = blockIdx.x;            // b*2048 + l
  int b = row >> 11, l = row & 2047;
  int c = threadIdx.x;
  float mu = stats[b * 2], rstd = stats[b * 2 + 1];
  float v = x[(size_t)b * 524288 + (size_t)c * 2048 + l];
  t[(size_t)row * 256 + c] = (v - mu) * rstd * gw[c] + gb[c];
}

// ---------------- generic batched GEMM: C = A(M,K) * B(N,K)^T ----------------
__global__ __launch_bounds__(256) void gemm_nt_k(const float* __restrict__ A, int lda, long sA,
                                                 const float* __restrict__ Bw, int ldb, long sB,
                                                 float* __restrict__ C, int ldc, long sC,
                                                 int M, int N, int K, int flipmask) {
  int zb = blockIdx.z;
  A  += (size_t)zb * sA;
  Bw += (size_t)zb * sB;
  C  += (size_t)zb * sC;
  int m0 = blockIdx.y * 64, n0 = blockIdx.x * 64;
  __shared__ float As[16][65];
  __shared__ float Bs[16][65];
  int tid = threadIdx.x;
  int tx = tid & 15, ty = tid >> 4;
  float acc[4][4] = {};
  for (int k0 = 0; k0 < K; k0 += 16) {
#pragma unroll
    for (int i = 0; i < 4; i++) {
      int lin = tid + i * 256;
      int r = lin >> 4, kk = lin & 15;
      int gm = m0 + r;
      int ga = gm ^ flipmask;
      As[kk][r] = (gm < M) ? A[(size_t)ga * lda + k0 + kk] : 0.f;
      int gn = n0 + r;
      Bs[kk][r] = (gn < N) ? Bw[(size_t)gn * ldb + k0 + kk] : 0.f;
    }
    __syncthreads();
#pragma unroll
    for (int kk = 0; kk < 16; kk++) {
      float a[4], bb[4];
#pragma unroll
      for (int i = 0; i < 4; i++) a[i] = As[kk][ty + i * 16];
#pragma unroll
      for (int j = 0; j < 4; j++) bb[j] = Bs[kk][tx + j * 16];
#pragma unroll
      for (int i = 0; i < 4; i++)
#pragma unroll
        for (int j = 0; j < 4; j++) acc[i][j] += a[i] * bb[j];
    }
    __syncthreads();
  }
#pragma unroll
  for (int i = 0; i < 4; i++) {
    int gm = m0 + ty + i * 16;
    if (gm >= M) continue;
#pragma unroll
    for (int j = 0; j < 4; j++) {
      int gn = n0 + tx + j * 16;
      if (gn < N) C[(size_t)gm * ldc + gn] = acc[i][j];
    }
  }
}

// ---------------- causal depthwise conv4 + silu ----------------
__global__ __launch_bounds__(256) void conv_k(const float* __restrict__ zx,
                                              const float* __restrict__ cw,
                                              const float* __restrict__ cb,
                                              float* __restrict__ xp) {
  int j = blockIdx.x * 256 + threadIdx.x;  // channel 0..1279
  int l = blockIdx.y, b = blockIdx.z;
  float acc = cb[j];
  size_t col = 1024 + j;
#pragma unroll
  for (int k = 0; k < 4; k++) {
    int ls = l - 3 + k;
    if (ls >= 0) acc += cw[j * 4 + k] * zx[(size_t)(b * 2048 + ls) * DPROJ + col];
  }
  xp[(size_t)(b * 2048 + l) * CONVD + j] = silu(acc);
}

// ---------------- dt = softplus(raw + bias), A = -exp(A_log)*dt ----------------
__global__ __launch_bounds__(256) void dt_k(const float* __restrict__ zx,
                                            const float* __restrict__ dtb,
                                            const float* __restrict__ Alog,
                                            float* __restrict__ dt,
                                            float* __restrict__ Ab) {
  int idx = blockIdx.x * 256 + threadIdx.x;  // 65536
  int row = idx >> 4, h = idx & 15;
  float rawv = zx[(size_t)row * DPROJ + 2304 + h] + dtb[h];
  float d = (rawv > 20.f) ? rawv : log1pf(expf(rawv));
  dt[idx] = d;
  Ab[idx] = -expf(Alog[h]) * d;
}

// ---------------- per-chunk inclusive scan of A ----------------
__global__ __launch_bounds__(256) void scan_k(const float* __restrict__ Ab,
                                              float* __restrict__ Acs,
                                              float* __restrict__ Ttot) {
  int h = blockIdx.x, c = blockIdx.y, b = blockIdx.z;
  int l = threadIdx.x;
  __shared__ float buf0[256], buf1[256];
  buf0[l] = Ab[(size_t)(b * 2048 + c * 256 + l) * 16 + h];
  __syncthreads();
  float* src = buf0;
  float* dst = buf1;
  for (int off = 1; off < 256; off <<= 1) {
    float v = src[l];
    if (l >= off) v += src[l - off];
    dst[l] = v;
    __syncthreads();
    float* tmp = src; src = dst; dst = tmp;
  }
  float s = src[l];
  int chidx = (b * NCH + c) * NH + h;
  Acs[(size_t)chidx * 256 + l] = s;
  if (l == 255) Ttot[chidx] = s;
}

// ---------------- Y_diag: per (h,c,b), thread = row l ----------------
__global__ __launch_bounds__(256) void ydiag_k(const float* __restrict__ Acs,
                                               const float* __restrict__ dtb,
                                               const float* __restrict__ CB,
                                               const float* __restrict__ xp,
                                               float* __restrict__ yhp) {
  int h = blockIdx.x, c = blockIdx.y, b = blockIdx.z;
  int l = threadIdx.x;
  __shared__ float sA[256], sdt[256];
  __shared__ float4 Xt[64][16];
  int row0 = b * 2048 + c * 256;
  int chidx = (b * NCH + c) * NH + h;
  sA[l] = Acs[(size_t)chidx * 256 + l];
  sdt[l] = dtb[(size_t)(row0 + l) * 16 + h];
  __syncthreads();
  float4 acc[16];
#pragma unroll
  for (int j = 0; j < 16; j++) acc[j] = make_float4(0.f, 0.f, 0.f, 0.f);
  const float* CBrow = CB + (size_t)(b * NCH + c) * 65536 + (size_t)l * 256;
  float Al = sA[l];
  for (int st = 0; st < 4; ++st) {
    {  // stage dt*x tile (64 rows x 64 p)
      int r = threadIdx.x >> 2;
      int cb4 = (threadIdx.x & 3) * 4;
      const float4* src = (const float4*)(xp + (size_t)(row0 + st * 64 + r) * CONVD + h * 64) + cb4;
      float sc = sdt[st * 64 + r];
#pragma unroll
      for (int q = 0; q < 4; q++) {
        float4 v = src[q];
        v.x *= sc; v.y *= sc; v.z *= sc; v.w *= sc;
        Xt[r][cb4 + q] = v;
      }
    }
    __syncthreads();
    int smax = l - st * 64 + 1;
    if (smax > 64) smax = 64;
    for (int s = 0; s < smax; ++s) {
      int gs = st * 64 + s;
      float w = __expf(Al - sA[gs]) * CBrow[gs];
#pragma unroll
      for (int j = 0; j < 16; j++) {
        float4 xv = Xt[s][j];
        acc[j].x += w * xv.x; acc[j].y += w * xv.y;
        acc[j].z += w * xv.z; acc[j].w += w * xv.w;
      }
    }
    __syncthreads();
  }
  float4* dst = (float4*)(yhp + (size_t)(row0 + l) * 1024 + h * 64);
#pragma unroll
  for (int j = 0; j < 16; j++) dst[j] = acc[j];
}

// ---------------- chunk states: states[p,n] = sum_l decay*dt*x[l,p]*B[l,n] ----------------
__global__ __launch_bounds__(256) void states_k(const float* __restrict__ Acs,
                                                const float* __restrict__ Ttot,
                                                const float* __restrict__ dtb,
                                                const float* __restrict__ xp,
                                                float* __restrict__ stout) {
  int h = blockIdx.x, c = blockIdx.y, b = blockIdx.z;
  int tid = threadIdx.x;
  __shared__ float sXs[256];
  __shared__ float Xd[32][64];
  __shared__ float Bt[32][128];
  int row0 = b * 2048 + c * 256;
  int chidx = (b * NCH + c) * NH + h;
  {
    float a = Acs[(size_t)chidx * 256 + tid];
    float Tt = Ttot[chidx];
    sXs[tid] = dtb[(size_t)(row0 + tid) * 16 + h] * __expf(Tt - a);
  }
  __syncthreads();
  float4 acc[8];
#pragma unroll
  for (int j = 0; j < 8; j++) acc[j] = make_float4(0.f, 0.f, 0.f, 0.f);
  int p = tid & 63, ng = tid >> 6;
  for (int lt = 0; lt < 8; ++lt) {
#pragma unroll
    for (int i = 0; i < 8; i++) {
      int lin = tid + i * 256;
      int r = lin >> 6, pp = lin & 63;
      Xd[r][pp] = xp[(size_t)(row0 + lt * 32 + r) * CONVD + h * 64 + pp] * sXs[lt * 32 + r];
    }
#pragma unroll
    for (int i = 0; i < 16; i++) {
      int lin = tid + i * 256;
      int r = lin >> 7, nn = lin & 127;
      Bt[r][nn] = xp[(size_t)(row0 + lt * 32 + r) * CONVD + 1024 + nn];
    }
    __syncthreads();
#pragma unroll
    for (int r = 0; r < 32; r++) {
      float xv = Xd[r][p];
      const float4* bp = (const float4*)&Bt[r][ng * 32];
#pragma unroll
      for (int j = 0; j < 8; j++) {
        float4 bv = bp[j];
        acc[j].x += xv * bv.x; acc[j].y += xv * bv.y;
        acc[j].z += xv * bv.z; acc[j].w += xv * bv.w;
      }
    }
    __syncthreads();
  }
  float4* dst = (float4*)(stout + (size_t)chidx * 8192 + p * 128 + ng * 32);
#pragma unroll
  for (int j = 0; j < 8; j++) dst[j] = acc[j];
}

// ---------------- inter-chunk recurrence ----------------
__global__ __launch_bounds__(256) void recur_k(const float* __restrict__ st,
                                               const float* __restrict__ Ttot,
                                               float* __restrict__ Sin) {
  int h = blockIdx.x, b = blockIdx.y;
  int e0 = threadIdx.x * 32;
  float4 s[8];
#pragma unroll
  for (int j = 0; j < 8; j++) s[j] = make_float4(0.f, 0.f, 0.f, 0.f);
  for (int c = 0; c < 8; c++) {
    int chidx = (b * NCH + c) * NH + h;
    size_t base = (size_t)chidx * 8192 + e0;
    float4* so = (float4*)(Sin + base);
    const float4* si = (const float4*)(st + base);
    float dec = __expf(Ttot[chidx]);
#pragma unroll
    for (int j = 0; j < 8; j++) {
      so[j] = s[j];
      float4 v = si[j];
      s[j].x = s[j].x * dec + v.x; s[j].y = s[j].y * dec + v.y;
      s[j].z = s[j].z * dec + v.z; s[j].w = s[j].w * dec + v.w;
    }
  }
}

// ---------------- Y_off: yhp += exp(Acs[l]) * C[l,:] @ Sin[p,:]^T ----------------
__global__ __launch_bounds__(256) void yoff_k(const float* __restrict__ Acs,
                                              const float* __restrict__ xp,
                                              const float* __restrict__ Sin,
                                              float* __restrict__ yhp) {
  int h = blockIdx.x, c = blockIdx.y, b = blockIdx.z;
  int l = threadIdx.x;
  __shared__ float sA[256];
  __shared__ float sC[256][33];
  __shared__ float sS[32][72];
  int row0 = b * 2048 + c * 256;
  int chidx = (b * NCH + c) * NH + h;
  sA[l] = Acs[(size_t)chidx * 256 + l];
  const float* Sbase = Sin + (size_t)chidx * 8192;
  float4 acc[16];
#pragma unroll
  for (int j = 0; j < 16; j++) acc[j] = make_float4(0.f, 0.f, 0.f, 0.f);
  for (int nt = 0; nt < 4; ++nt) {
#pragma unroll
    for (int i = 0; i < 32; i++) {
      int lin = threadIdx.x + i * 256;
      int r = lin >> 5, nn = lin & 31;
      sC[r][nn] = xp[(size_t)(row0 + r) * CONVD + 1152 + nt * 32 + nn];
    }
#pragma unroll
    for (int i = 0; i < 8; i++) {
      int lin = threadIdx.x + i * 256;
      int pp = lin >> 5, nn = lin & 31;
      sS[nn][pp] = Sbase[(size_t)pp * 128 + nt * 32 + nn];
    }
    __syncthreads();
#pragma unroll 4
    for (int nn = 0; nn < 32; ++nn) {
      float cl = sC[l][nn];
      const float4* sp = (const float4*)&sS[nn][0];
#pragma unroll
      for (int j = 0; j < 16; j++) {
        float4 sv = sp[j];
        acc[j].x += cl * sv.x; acc[j].y += cl * sv.y;
        acc[j].z += cl * sv.z; acc[j].w += cl * sv.w;
      }
    }
    __syncthreads();
  }
  float sc = __expf(sA[l]);
  float4* dst = (float4*)(yhp + (size_t)(row0 + l) * 1024 + h * 64);
#pragma unroll
  for (int j = 0; j < 16; j++) {
    float4 o = dst[j];
    o.x += sc * acc[j].x; o.y += sc * acc[j].y;
    o.z += sc * acc[j].z; o.w += sc * acc[j].w;
    dst[j] = o;
  }
}

// ---------------- gate with silu(z), add x*D, RMS norm ----------------
__global__ __launch_bounds__(256) void gate_rms_k(float* __restrict__ yhp,
                                                  const float* __restrict__ xp,
                                                  const float* __restrict__ zx,
                                                  const float* __restrict__ Dv,
                                                  const float* __restrict__ nw) {
  int row = blockIdx.x;
  float g[4];
  float ss = 0.f;
#pragma unroll
  for (int k = 0; k < 4; k++) {
    int i = threadIdx.x + k * 256;
    int h = i >> 6;
    float y = yhp[(size_t)row * 1024 + i] + xp[(size_t)row * CONVD + i] * Dv[h];
    float z = zx[(size_t)row * DPROJ + i];
    float gg = y * silu(z);
    ss += gg * gg;
    g[k] = gg;
  }
  for (int o = 32; o > 0; o >>= 1) ss += __shfl_down(ss, o);
  __shared__ float red[5];
  int wid = threadIdx.x >> 6;
  if ((threadIdx.x & 63) == 0) red[wid] = ss;
  __syncthreads();
  if (threadIdx.x == 0) red[4] = red[0] + red[1] + red[2] + red[3];
  __syncthreads();
  float rstd = rsqrtf(red[4] / 1024.f + 1e-5f);
#pragma unroll
  for (int k = 0; k < 4; k++) {
    int i = threadIdx.x + k * 256;
    yhp[(size_t)row * 1024 + i] = g[k] * rstd * nw[i];
  }
}

// ---------------- build r = [yf + t, yb_flipped + t] ----------------
__global__ __launch_bounds__(256) void build_r_k(const float* __restrict__ yf,
                                                 const float* __restrict__ yb,
                                                 const float* __restrict__ t,
                                                 float* __restrict__ r) {
  int row = blockIdx.x;
  int c = threadIdx.x;
  float tv = t[(size_t)row * 256 + c];
  r[(size_t)row * 512 + c]       = yf[(size_t)row * 256 + c] + tv;
  r[(size_t)row * 512 + 256 + c] = yb[(size_t)(row ^ 2047) * 256 + c] + tv;
}

// ---------------- out = x + pr^T + proj_b ----------------
__global__ __launch_bounds__(256) void final_add_k(const float* __restrict__ x,
                                                   const float* __restrict__ pr,
                                                   const float* __restrict__ pb,
                                                   float* __restrict__ out) {
  int bc = blockIdx.x;  // b*256 + ch
  int b = bc >> 8, ch = bc & 255;
  float pbv = pb[ch];
#pragma unroll
  for (int i = 0; i < 8; i++) {
    int l = threadIdx.x + i * 256;
    size_t o = (size_t)b * 524288 + (size_t)ch * 2048 + l;
    out[o] = x[o] + pr[(size_t)(b * 2048 + l) * 256 + ch] + pbv;
  }
}

}  // namespace

extern "C" void kernel_launch(void* const* d_in, const int* in_sizes, int n_in,
                              void* d_out, int out_size, void* d_ws, size_t ws_size,
                              hipStream_t stream) {
  (void)in_sizes; (void)n_in; (void)out_size; (void)ws_size;
  const float* x      = (const float*)d_in[0];
  const float* gn_w   = (const float*)d_in[1];
  const float* gn_b   = (const float*)d_in[2];
  const float* proj_w = (const float*)d_in[3];
  const float* proj_b = (const float*)d_in[4];
  float* out = (float*)d_out;
  float* ws  = (float*)d_ws;
  float* scr = ws + F_SCR;

  // groupnorm + transpose
  stats_partial_k<<<dim3(64, 2), 256, 0, stream>>>(x, ws + F_PART);
  stats_final_k<<<2, 64, 0, stream>>>(ws + F_PART, ws + F_STATS);
  norm_t_k<<<4096, 256, 0, stream>>>(x, gn_w, gn_b, ws + F_STATS, ws + F_T);

  for (int dir = 0; dir < 2; dir++) {
    const float* in_w    = (const float*)d_in[5 + dir * 8];
    const float* conv_w  = (const float*)d_in[6 + dir * 8];
    const float* conv_b  = (const float*)d_in[7 + dir * 8];
    const float* dt_bias = (const float*)d_in[8 + dir * 8];
    const float* A_log   = (const float*)d_in[9 + dir * 8];
    const float* Dv      = (const float*)d_in[10 + dir * 8];
    const float* norm_w  = (const float*)d_in[11 + dir * 8];
    const float* out_w   = (const float*)d_in[12 + dir * 8];
    float* yout = ws + (dir ? F_YB : F_YF);
    int flip = dir ? 2047 : 0;

    // in_proj: zxbcdt = t(_flipped) @ in_w^T   (4096 x 2320, K=256)
    gemm_nt_k<<<dim3((DPROJ + 63) / 64, 64, 1), 256, 0, stream>>>(
        ws + F_T, 256, 0, in_w, 256, 0, scr + S_ZX, DPROJ, 0, 4096, DPROJ, 256, flip);
    // conv + silu
    conv_k<<<dim3(5, 2048, 2), 256, 0, stream>>>(scr + S_ZX, conv_w, conv_b, scr + S_XP);
    // dt / A
    dt_k<<<256, 256, 0, stream>>>(scr + S_ZX, dt_bias, A_log, scr + S_DT, scr + S_A);
    // per-chunk scan
    scan_k<<<dim3(NH, NCH, 2), 256, 0, stream>>>(scr + S_A, scr + S_ACS, scr + S_TT);
    // CB = C @ B^T per (b,chunk): batched GEMM, 256x256, K=128
    gemm_nt_k<<<dim3(4, 4, 16), 256, 0, stream>>>(
        scr + S_XP + 1152, CONVD, 256L * CONVD,
        scr + S_XP + 1024, CONVD, 256L * CONVD,
        scr + S_CB, 256, 65536L, 256, 256, 128, 0);
    // Y_diag
    ydiag_k<<<dim3(NH, NCH, 2), 256, 0, stream>>>(scr + S_ACS, scr + S_DT, scr + S_CB,
                                                  scr + S_XP, scr + S_YHP);
    // chunk states
    states_k<<<dim3(NH, NCH, 2), 256, 0, stream>>>(scr + S_ACS, scr + S_TT, scr + S_DT,
                                                   scr + S_XP, scr + S_ST);
    // recurrence over chunks
    recur_k<<<dim3(NH, 2), 256, 0, stream>>>(scr + S_ST, scr + S_TT, scr + S_SIN);
    // Y_off (+=)
    yoff_k<<<dim3(NH, NCH, 2), 256, 0, stream>>>(scr + S_ACS, scr + S_XP, scr + S_SIN,
                                                 scr + S_YHP);
    // gate + RMS norm (in place on yhp)
    gate_rms_k<<<4096, 256, 0, stream>>>(scr + S_YHP, scr + S_XP, scr + S_ZX, Dv, norm_w);
    // out_proj: yout = yhp @ out_w^T   (4096 x 256, K=1024)
    gemm_nt_k<<<dim3(4, 64, 1), 256, 0, stream>>>(
        scr + S_YHP, 1024, 0, out_w, 1024, 0, yout, 256, 0, 4096, 256, 1024, 0);
  }

  // r = [yf + t, yb_flip + t]; pr = r @ proj_w^T; out = x + pr^T + proj_b
  build_r_k<<<4096, 256, 0, stream>>>(ws + F_YF, ws + F_YB, ws + F_T, scr + S_R);
  gemm_nt_k<<<dim3(4, 64, 1), 256, 0, stream>>>(
      scr + S_R, 512, 0, proj_w, 512, 0, scr + S_PR, 256, 0, 4096, 256, 512, 0);
  final_add_k<<<512, 256, 0, stream>>>(x, scr + S_PR, proj_b, out);
}

// Round 2
// 880.327 us; speedup vs baseline: 1.5040x; 1.5040x over previous
//
#include <hip/hip_runtime.h>
#include <math.h>

namespace {

constexpr int NH    = 16;
constexpr int CONVD = 1280;
constexpr int DPROJ = 2320;
constexpr int NCH   = 8;

// workspace layout (in floats)
constexpr size_t F_STATS = 0;                 // 4: mu0,rstd0,mu1,rstd1
constexpr size_t F_PART  = 4;                 // 256: partial sums
constexpr size_t F_T     = 260;               // normalized transposed input (B,L,256)
constexpr size_t SZ_T    = 2ull * 2048 * 256; // 1048576
constexpr size_t F_YF    = F_T + SZ_T;
constexpr size_t F_YB    = F_YF + SZ_T;
constexpr size_t F_SCR   = F_YB + SZ_T;       // per-direction scratch (reused)

constexpr size_t S_ZX  = 0;                   // (B*L, 2320)
constexpr size_t SZ_ZX = 2ull * 2048 * 2320;  // 9502720
constexpr size_t S_XP  = S_ZX + SZ_ZX;        // (B*L, 1280) post-conv
constexpr size_t SZ_XP = 2ull * 2048 * 1280;  // 5242880
constexpr size_t S_DT  = S_XP + SZ_XP;        // (B*L,16)
constexpr size_t S_A   = S_DT + 65536;        // (B*L,16)
constexpr size_t S_ACS = S_A + 65536;         // (B*NCH*NH,256)
constexpr size_t S_TT  = S_ACS + 65536;       // (B*NCH*NH)
constexpr size_t S_CB  = S_TT + 256;          // (B*NCH,256,256)
constexpr size_t S_ST  = S_CB + 1048576;      // (B*NCH*NH, 64*128) fp32
constexpr size_t S_SIN = S_ST + 2097152;      // same
constexpr size_t S_YHP = S_SIN + 2097152;     // (B*L,1024)
constexpr size_t SZ_SCR = S_YHP + 4194304;
// overlays (bf16 stored as ushort), inside scratch:
//   bc16  -> scr + S_SIN   (needed only for CB gemm, before recur_k writes S_SIN)
//   yhp16 -> scr + S_ST    (written in gate_rms after recur_k is done with S_ST)
//   r16   -> scr + S_ZX    (after both directions)
constexpr size_t S_PR = S_ZX + 2097152;       // pr fp32 (B*L,256)
// persistent bf16 buffers appended after scratch:
constexpr size_t F_BF = F_SCR + SZ_SCR;       // ushort region base (as float offset)

typedef __bf16 bf16x8 __attribute__((ext_vector_type(8)));
typedef float  f32x4  __attribute__((ext_vector_type(4)));

__device__ __forceinline__ float silu(float v) { return v / (1.f + expf(-v)); }

__device__ __forceinline__ unsigned short f2bf(float f) {
  unsigned int u = __float_as_uint(f);
  return (unsigned short)((u + 0x7fffu + ((u >> 16) & 1u)) >> 16);
}

// ---------------- groupnorm stats ----------------
__global__ __launch_bounds__(256) void stats_partial_k(const float* __restrict__ x,
                                                       float* __restrict__ part) {
  int b = blockIdx.y, seg = blockIdx.x;
  const float4* base = (const float4*)(x + (size_t)b * 524288 + (size_t)seg * 8192);
  float s = 0.f, q = 0.f;
#pragma unroll
  for (int i = 0; i < 8; i++) {
    float4 v = base[threadIdx.x + i * 256];
    s += v.x + v.y + v.z + v.w;
    q += v.x * v.x + v.y * v.y + v.z * v.z + v.w * v.w;
  }
  for (int o = 32; o > 0; o >>= 1) { s += __shfl_down(s, o); q += __shfl_down(q, o); }
  __shared__ float ss[4], qq[4];
  int wid = threadIdx.x >> 6;
  if ((threadIdx.x & 63) == 0) { ss[wid] = s; qq[wid] = q; }
  __syncthreads();
  if (threadIdx.x == 0) {
    part[(b * 64 + seg) * 2]     = ss[0] + ss[1] + ss[2] + ss[3];
    part[(b * 64 + seg) * 2 + 1] = qq[0] + qq[1] + qq[2] + qq[3];
  }
}

__global__ __launch_bounds__(64) void stats_final_k(const float* __restrict__ part,
                                                    float* __restrict__ stats) {
  int b = blockIdx.x;
  float s = part[(b * 64 + threadIdx.x) * 2];
  float q = part[(b * 64 + threadIdx.x) * 2 + 1];
  for (int o = 32; o > 0; o >>= 1) { s += __shfl_down(s, o); q += __shfl_down(q, o); }
  if (threadIdx.x == 0) {
    float mu  = s / 524288.f;
    float var = q / 524288.f - mu * mu;
    stats[b * 2]     = mu;
    stats[b * 2 + 1] = rsqrtf(var + 1.1920929e-07f);
  }
}

// ---------------- normalize + transpose (fp32 + bf16 copies) ----------------
__global__ __launch_bounds__(256) void norm_t_k(const float* __restrict__ x,
                                                const float* __restrict__ gw,
                                                const float* __restrict__ gb,
                                                const float* __restrict__ stats,
                                                float* __restrict__ t,
                                                unsigned short* __restrict__ t16) {
  int row = blockIdx.x;            // b*2048 + l
  int b = row >> 11, l = row & 2047;
  int c = threadIdx.x;
  float mu = stats[b * 2], rstd = stats[b * 2 + 1];
  float v = x[(size_t)b * 524288 + (size_t)c * 2048 + l];
  float o = (v - mu) * rstd * gw[c] + gb[c];
  t[(size_t)row * 256 + c] = o;
  t16[(size_t)row * 256 + c] = f2bf(o);
}

// ---------------- generic fp32 -> bf16 convert ----------------
__global__ __launch_bounds__(256) void cvt_k(const float* __restrict__ in,
                                             unsigned short* __restrict__ out, int n4) {
  int i = blockIdx.x * 256 + threadIdx.x;
  if (i < n4) {
    float4 v = ((const float4*)in)[i];
    ushort4 o;
    o.x = f2bf(v.x); o.y = f2bf(v.y); o.z = f2bf(v.z); o.w = f2bf(v.w);
    ((ushort4*)out)[i] = o;
  }
}

// ---------------- bf16 MFMA GEMM: C(f32) = A(M,K) * B(N,K)^T ----------------
// 128x128 tile, BK=32, 4 waves (2x2), 16x16x32 MFMA. flip XORs A's row index.
__global__ __launch_bounds__(256) void gemm_bf16_k(
    const unsigned short* __restrict__ A, int lda, long sA,
    const unsigned short* __restrict__ B, int ldb, long sB,
    float* __restrict__ C, int ldc, long sC,
    int M, int N, int K, int flip) {
  int zb = blockIdx.z;
  A += (size_t)zb * sA;
  B += (size_t)zb * sB;
  C += (size_t)zb * sC;
  int m0 = blockIdx.y * 128, n0 = blockIdx.x * 128;
  __shared__ unsigned short As[128][40];   // +8 pad: 80B row stride, 16B aligned
  __shared__ unsigned short Bs[128][40];
  int tid = threadIdx.x;
  int lane = tid & 63, wid = tid >> 6;
  int wr = (wid >> 1) * 64, wc = (wid & 1) * 64;
  int fr = lane & 15, fq = lane >> 4;
  int sr = tid >> 2;          // staging row (0..63), +64 for second half
  int sk = (tid & 3) * 8;     // staging k offset
  f32x4 acc[4][4] = {};
  for (int k0 = 0; k0 < K; k0 += 32) {
#pragma unroll
    for (int i = 0; i < 2; i++) {
      int r = sr + i * 64;
      int gm = (m0 + r) ^ flip;
      *(bf16x8*)&As[r][sk] = *(const bf16x8*)&A[(size_t)gm * lda + k0 + sk];
      int gn = n0 + r;
      if (gn >= N) gn = N - 1;
      *(bf16x8*)&Bs[r][sk] = *(const bf16x8*)&B[(size_t)gn * ldb + k0 + sk];
    }
    __syncthreads();
    bf16x8 a[4], b[4];
#pragma unroll
    for (int m = 0; m < 4; m++) a[m] = *(const bf16x8*)&As[wr + m * 16 + fr][fq * 8];
#pragma unroll
    for (int n = 0; n < 4; n++) b[n] = *(const bf16x8*)&Bs[wc + n * 16 + fr][fq * 8];
#pragma unroll
    for (int m = 0; m < 4; m++)
#pragma unroll
      for (int n = 0; n < 4; n++)
        acc[m][n] = __builtin_amdgcn_mfma_f32_16x16x32_bf16(a[m], b[n], acc[m][n], 0, 0, 0);
    __syncthreads();
  }
#pragma unroll
  for (int m = 0; m < 4; m++) {
    int row = m0 + wr + m * 16 + fq * 4;
#pragma unroll
    for (int n = 0; n < 4; n++) {
      int col = n0 + wc + n * 16 + fr;
      if (col < N) {
#pragma unroll
        for (int j = 0; j < 4; j++) C[(size_t)(row + j) * ldc + col] = acc[m][n][j];
      }
    }
  }
}

// ---------------- causal depthwise conv4 + silu ----------------
__global__ __launch_bounds__(256) void conv_k(const float* __restrict__ zx,
                                              const float* __restrict__ cw,
                                              const float* __restrict__ cb,
                                              float* __restrict__ xp) {
  int j = blockIdx.x * 256 + threadIdx.x;  // channel 0..1279
  int l = blockIdx.y, b = blockIdx.z;
  float acc = cb[j];
  size_t col = 1024 + j;
#pragma unroll
  for (int k = 0; k < 4; k++) {
    int ls = l - 3 + k;
    if (ls >= 0) acc += cw[j * 4 + k] * zx[(size_t)(b * 2048 + ls) * DPROJ + col];
  }
  xp[(size_t)(b * 2048 + l) * CONVD + j] = silu(acc);
}

// ---------------- bf16 copy of B/C section of xp ----------------
__global__ __launch_bounds__(256) void cvt_bc_k(const float* __restrict__ xp,
                                                unsigned short* __restrict__ bc16) {
  int row = blockIdx.x, c = threadIdx.x;
  bc16[(size_t)row * 256 + c] = f2bf(xp[(size_t)row * CONVD + 1024 + c]);
}

// ---------------- dt in fp32 (direct dot against t), A = -exp(A_log)*dt ----------------
__global__ __launch_bounds__(256) void dtg_k(const float* __restrict__ t,
                                             const float* __restrict__ in_w,
                                             const float* __restrict__ dtb,
                                             const float* __restrict__ Alog,
                                             float* __restrict__ dt,
                                             float* __restrict__ Ab, int flip) {
  int idx = blockIdx.x * 256 + threadIdx.x;  // 65536
  int row = idx >> 4, h = idx & 15;
  int ga = row ^ flip;
  const float4* t4 = (const float4*)(t + (size_t)ga * 256);
  const float4* w4 = (const float4*)(in_w + (size_t)(2304 + h) * 256);
  float s = 0.f;
#pragma unroll 8
  for (int k = 0; k < 64; k++) {
    float4 a = t4[k], b = w4[k];
    s += a.x * b.x + a.y * b.y + a.z * b.z + a.w * b.w;
  }
  float rawv = s + dtb[h];
  float d = (rawv > 20.f) ? rawv : log1pf(expf(rawv));
  dt[idx] = d;
  Ab[idx] = -expf(Alog[h]) * d;
}

// ---------------- per-chunk inclusive scan of A ----------------
__global__ __launch_bounds__(256) void scan_k(const float* __restrict__ Ab,
                                              float* __restrict__ Acs,
                                              float* __restrict__ Ttot) {
  int h = blockIdx.x, c = blockIdx.y, b = blockIdx.z;
  int l = threadIdx.x;
  __shared__ float buf0[256], buf1[256];
  buf0[l] = Ab[(size_t)(b * 2048 + c * 256 + l) * 16 + h];
  __syncthreads();
  float* src = buf0;
  float* dst = buf1;
  for (int off = 1; off < 256; off <<= 1) {
    float v = src[l];
    if (l >= off) v += src[l - off];
    dst[l] = v;
    __syncthreads();
    float* tmp = src; src = dst; dst = tmp;
  }
  float s = src[l];
  int chidx = (b * NCH + c) * NH + h;
  Acs[(size_t)chidx * 256 + l] = s;
  if (l == 255) Ttot[chidx] = s;
}

// ---------------- Y_diag ----------------
__global__ __launch_bounds__(256) void ydiag_k(const float* __restrict__ Acs,
                                               const float* __restrict__ dtb,
                                               const float* __restrict__ CB,
                                               const float* __restrict__ xp,
                                               float* __restrict__ yhp) {
  int h = blockIdx.x, c = blockIdx.y, b = blockIdx.z;
  int l = threadIdx.x;
  __shared__ float sA[256], sdt[256];
  __shared__ float4 Xt[64][16];
  int row0 = b * 2048 + c * 256;
  int chidx = (b * NCH + c) * NH + h;
  sA[l] = Acs[(size_t)chidx * 256 + l];
  sdt[l] = dtb[(size_t)(row0 + l) * 16 + h];
  __syncthreads();
  float4 acc[16];
#pragma unroll
  for (int j = 0; j < 16; j++) acc[j] = make_float4(0.f, 0.f, 0.f, 0.f);
  const float* CBrow = CB + (size_t)(b * NCH + c) * 65536 + (size_t)l * 256;
  float Al = sA[l];
  for (int st = 0; st < 4; ++st) {
    {
      int r = threadIdx.x >> 2;
      int cb4 = (threadIdx.x & 3) * 4;
      const float4* src = (const float4*)(xp + (size_t)(row0 + st * 64 + r) * CONVD + h * 64) + cb4;
      float sc = sdt[st * 64 + r];
#pragma unroll
      for (int q = 0; q < 4; q++) {
        float4 v = src[q];
        v.x *= sc; v.y *= sc; v.z *= sc; v.w *= sc;
        Xt[r][cb4 + q] = v;
      }
    }
    __syncthreads();
    int smax = l - st * 64 + 1;
    if (smax > 64) smax = 64;
    for (int s = 0; s < smax; ++s) {
      int gs = st * 64 + s;
      float w = __expf(Al - sA[gs]) * CBrow[gs];
#pragma unroll
      for (int j = 0; j < 16; j++) {
        float4 xv = Xt[s][j];
        acc[j].x += w * xv.x; acc[j].y += w * xv.y;
        acc[j].z += w * xv.z; acc[j].w += w * xv.w;
      }
    }
    __syncthreads();
  }
  float4* dst = (float4*)(yhp + (size_t)(row0 + l) * 1024 + h * 64);
#pragma unroll
  for (int j = 0; j < 16; j++) dst[j] = acc[j];
}

// ---------------- chunk states ----------------
__global__ __launch_bounds__(256) void states_k(const float* __restrict__ Acs,
                                                const float* __restrict__ Ttot,
                                                const float* __restrict__ dtb,
                                                const float* __restrict__ xp,
                                                float* __restrict__ stout) {
  int h = blockIdx.x, c = blockIdx.y, b = blockIdx.z;
  int tid = threadIdx.x;
  __shared__ float sXs[256];
  __shared__ float Xd[32][64];
  __shared__ float Bt[32][128];
  int row0 = b * 2048 + c * 256;
  int chidx = (b * NCH + c) * NH + h;
  {
    float a = Acs[(size_t)chidx * 256 + tid];
    float Tt = Ttot[chidx];
    sXs[tid] = dtb[(size_t)(row0 + tid) * 16 + h] * __expf(Tt - a);
  }
  __syncthreads();
  float4 acc[8];
#pragma unroll
  for (int j = 0; j < 8; j++) acc[j] = make_float4(0.f, 0.f, 0.f, 0.f);
  int p = tid & 63, ng = tid >> 6;
  for (int lt = 0; lt < 8; ++lt) {
#pragma unroll
    for (int i = 0; i < 8; i++) {
      int lin = tid + i * 256;
      int r = lin >> 6, pp = lin & 63;
      Xd[r][pp] = xp[(size_t)(row0 + lt * 32 + r) * CONVD + h * 64 + pp] * sXs[lt * 32 + r];
    }
#pragma unroll
    for (int i = 0; i < 16; i++) {
      int lin = tid + i * 256;
      int r = lin >> 7, nn = lin & 127;
      Bt[r][nn] = xp[(size_t)(row0 + lt * 32 + r) * CONVD + 1024 + nn];
    }
    __syncthreads();
#pragma unroll
    for (int r = 0; r < 32; r++) {
      float xv = Xd[r][p];
      const float4* bp = (const float4*)&Bt[r][ng * 32];
#pragma unroll
      for (int j = 0; j < 8; j++) {
        float4 bv = bp[j];
        acc[j].x += xv * bv.x; acc[j].y += xv * bv.y;
        acc[j].z += xv * bv.z; acc[j].w += xv * bv.w;
      }
    }
    __syncthreads();
  }
  float4* dst = (float4*)(stout + (size_t)chidx * 8192 + p * 128 + ng * 32);
#pragma unroll
  for (int j = 0; j < 8; j++) dst[j] = acc[j];
}

// ---------------- inter-chunk recurrence ----------------
__global__ __launch_bounds__(256) void recur_k(const float* __restrict__ st,
                                               const float* __restrict__ Ttot,
                                               float* __restrict__ Sin) {
  int h = blockIdx.x, b = blockIdx.y;
  int e0 = threadIdx.x * 32;
  float4 s[8];
#pragma unroll
  for (int j = 0; j < 8; j++) s[j] = make_float4(0.f, 0.f, 0.f, 0.f);
  for (int c = 0; c < 8; c++) {
    int chidx = (b * NCH + c) * NH + h;
    size_t base = (size_t)chidx * 8192 + e0;
    float4* so = (float4*)(Sin + base);
    const float4* si = (const float4*)(st + base);
    float dec = __expf(Ttot[chidx]);
#pragma unroll
    for (int j = 0; j < 8; j++) {
      so[j] = s[j];
      float4 v = si[j];
      s[j].x = s[j].x * dec + v.x; s[j].y = s[j].y * dec + v.y;
      s[j].z = s[j].z * dec + v.z; s[j].w = s[j].w * dec + v.w;
    }
  }
}

// ---------------- Y_off ----------------
__global__ __launch_bounds__(256) void yoff_k(const float* __restrict__ Acs,
                                              const float* __restrict__ xp,
                                              const float* __restrict__ Sin,
                                              float* __restrict__ yhp) {
  int h = blockIdx.x, c = blockIdx.y, b = blockIdx.z;
  int l = threadIdx.x;
  __shared__ float sA[256];
  __shared__ float sC[256][33];
  __shared__ float sS[32][72];
  int row0 = b * 2048 + c * 256;
  int chidx = (b * NCH + c) * NH + h;
  sA[l] = Acs[(size_t)chidx * 256 + l];
  const float* Sbase = Sin + (size_t)chidx * 8192;
  float4 acc[16];
#pragma unroll
  for (int j = 0; j < 16; j++) acc[j] = make_float4(0.f, 0.f, 0.f, 0.f);
  for (int nt = 0; nt < 4; ++nt) {
#pragma unroll
    for (int i = 0; i < 32; i++) {
      int lin = threadIdx.x + i * 256;
      int r = lin >> 5, nn = lin & 31;
      sC[r][nn] = xp[(size_t)(row0 + r) * CONVD + 1152 + nt * 32 + nn];
    }
#pragma unroll
    for (int i = 0; i < 8; i++) {
      int lin = threadIdx.x + i * 256;
      int pp = lin >> 5, nn = lin & 31;
      sS[nn][pp] = Sbase[(size_t)pp * 128 + nt * 32 + nn];
    }
    __syncthreads();
#pragma unroll 4
    for (int nn = 0; nn < 32; ++nn) {
      float cl = sC[l][nn];
      const float4* sp = (const float4*)&sS[nn][0];
#pragma unroll
      for (int j = 0; j < 16; j++) {
        float4 sv = sp[j];
        acc[j].x += cl * sv.x; acc[j].y += cl * sv.y;
        acc[j].z += cl * sv.z; acc[j].w += cl * sv.w;
      }
    }
    __syncthreads();
  }
  float sc = __expf(sA[l]);
  float4* dst = (float4*)(yhp + (size_t)(row0 + l) * 1024 + h * 64);
#pragma unroll
  for (int j = 0; j < 16; j++) {
    float4 o = dst[j];
    o.x += sc * acc[j].x; o.y += sc * acc[j].y;
    o.z += sc * acc[j].z; o.w += sc * acc[j].w;
    dst[j] = o;
  }
}

// ---------------- gate with silu(z), add x*D, RMS norm (+bf16 copy) ----------------
__global__ __launch_bounds__(256) void gate_rms_k(float* __restrict__ yhp,
                                                  const float* __restrict__ xp,
                                                  const float* __restrict__ zx,
                                                  const float* __restrict__ Dv,
                                                  const float* __restrict__ nw,
                                                  unsigned short* __restrict__ yhp16) {
  int row = blockIdx.x;
  float g[4];
  float ss = 0.f;
#pragma unroll
  for (int k = 0; k < 4; k++) {
    int i = threadIdx.x + k * 256;
    int h = i >> 6;
    float y = yhp[(size_t)row * 1024 + i] + xp[(size_t)row * CONVD + i] * Dv[h];
    float z = zx[(size_t)row * DPROJ + i];
    float gg = y * silu(z);
    ss += gg * gg;
    g[k] = gg;
  }
  for (int o = 32; o > 0; o >>= 1) ss += __shfl_down(ss, o);
  __shared__ float red[5];
  int wid = threadIdx.x >> 6;
  if ((threadIdx.x & 63) == 0) red[wid] = ss;
  __syncthreads();
  if (threadIdx.x == 0) red[4] = red[0] + red[1] + red[2] + red[3];
  __syncthreads();
  float rstd = rsqrtf(red[4] / 1024.f + 1e-5f);
#pragma unroll
  for (int k = 0; k < 4; k++) {
    int i = threadIdx.x + k * 256;
    float o = g[k] * rstd * nw[i];
    yhp[(size_t)row * 1024 + i] = o;
    yhp16[(size_t)row * 1024 + i] = f2bf(o);
  }
}

// ---------------- build r16 = bf16([yf + t, yb_flipped + t]) ----------------
__global__ __launch_bounds__(256) void build_r_k(const float* __restrict__ yf,
                                                 const float* __restrict__ yb,
                                                 const float* __restrict__ t,
                                                 unsigned short* __restrict__ r16) {
  int row = blockIdx.x;
  int c = threadIdx.x;
  float tv = t[(size_t)row * 256 + c];
  r16[(size_t)row * 512 + c]       = f2bf(yf[(size_t)row * 256 + c] + tv);
  r16[(size_t)row * 512 + 256 + c] = f2bf(yb[(size_t)(row ^ 2047) * 256 + c] + tv);
}

// ---------------- out = x + pr^T + proj_b ----------------
__global__ __launch_bounds__(256) void final_add_k(const float* __restrict__ x,
                                                   const float* __restrict__ pr,
                                                   const float* __restrict__ pb,
                                                   float* __restrict__ out) {
  int bc = blockIdx.x;  // b*256 + ch
  int b = bc >> 8, ch = bc & 255;
  float pbv = pb[ch];
#pragma unroll
  for (int i = 0; i < 8; i++) {
    int l = threadIdx.x + i * 256;
    size_t o = (size_t)b * 524288 + (size_t)ch * 2048 + l;
    out[o] = x[o] + pr[(size_t)(b * 2048 + l) * 256 + ch] + pbv;
  }
}

}  // namespace

extern "C" void kernel_launch(void* const* d_in, const int* in_sizes, int n_in,
                              void* d_out, int out_size, void* d_ws, size_t ws_size,
                              hipStream_t stream) {
  (void)in_sizes; (void)n_in; (void)out_size; (void)ws_size;
  const float* x      = (const float*)d_in[0];
  const float* gn_w   = (const float*)d_in[1];
  const float* gn_b   = (const float*)d_in[2];
  const float* proj_w = (const float*)d_in[3];
  const float* proj_b = (const float*)d_in[4];
  float* out = (float*)d_out;
  float* ws  = (float*)d_ws;
  float* scr = ws + F_SCR;

  unsigned short* t16     = (unsigned short*)(ws + F_BF);
  unsigned short* inw16   = t16 + 1048576;
  unsigned short* outw16  = inw16 + 593920;
  unsigned short* projw16 = outw16 + 262144;
  unsigned short* bc16    = (unsigned short*)(scr + S_SIN);  // overlay
  unsigned short* yhp16   = (unsigned short*)(scr + S_ST);   // overlay
  unsigned short* r16     = (unsigned short*)(scr + S_ZX);   // overlay (after dirs)

  // groupnorm + transpose (+bf16 t)
  stats_partial_k<<<dim3(64, 2), 256, 0, stream>>>(x, ws + F_PART);
  stats_final_k<<<2, 64, 0, stream>>>(ws + F_PART, ws + F_STATS);
  norm_t_k<<<4096, 256, 0, stream>>>(x, gn_w, gn_b, ws + F_STATS, ws + F_T, t16);
  cvt_k<<<(131072 / 4 + 255) / 256, 256, 0, stream>>>(proj_w, projw16, 131072 / 4);

  for (int dir = 0; dir < 2; dir++) {
    const float* in_w    = (const float*)d_in[5 + dir * 8];
    const float* conv_w  = (const float*)d_in[6 + dir * 8];
    const float* conv_b  = (const float*)d_in[7 + dir * 8];
    const float* dt_bias = (const float*)d_in[8 + dir * 8];
    const float* A_log   = (const float*)d_in[9 + dir * 8];
    const float* Dv      = (const float*)d_in[10 + dir * 8];
    const float* norm_w  = (const float*)d_in[11 + dir * 8];
    const float* out_w   = (const float*)d_in[12 + dir * 8];
    float* yout = ws + (dir ? F_YB : F_YF);
    int flip = dir ? 2047 : 0;

    cvt_k<<<(593920 / 4 + 255) / 256, 256, 0, stream>>>(in_w, inw16, 593920 / 4);
    cvt_k<<<(262144 / 4 + 255) / 256, 256, 0, stream>>>(out_w, outw16, 262144 / 4);

    // in_proj: zx = t(flip) @ in_w^T   (4096 x 2320, K=256)
    gemm_bf16_k<<<dim3(19, 32, 1), 256, 0, stream>>>(
        t16, 256, 0, inw16, 256, 0, scr + S_ZX, DPROJ, 0, 4096, DPROJ, 256, flip);
    // conv + silu
    conv_k<<<dim3(5, 2048, 2), 256, 0, stream>>>(scr + S_ZX, conv_w, conv_b, scr + S_XP);
    // bf16 copy of B/C
    cvt_bc_k<<<4096, 256, 0, stream>>>(scr + S_XP, bc16);
    // dt / A in fp32
    dtg_k<<<256, 256, 0, stream>>>(ws + F_T, in_w, dt_bias, A_log, scr + S_DT, scr + S_A, flip);
    // per-chunk scan
    scan_k<<<dim3(NH, NCH, 2), 256, 0, stream>>>(scr + S_A, scr + S_ACS, scr + S_TT);
    // CB = C @ B^T per (b,chunk): bf16 MFMA, 256x256, K=128
    gemm_bf16_k<<<dim3(2, 2, 16), 256, 0, stream>>>(
        bc16 + 128, 256, 65536L, bc16, 256, 65536L,
        scr + S_CB, 256, 65536L, 256, 256, 128, 0);
    // Y_diag
    ydiag_k<<<dim3(NH, NCH, 2), 256, 0, stream>>>(scr + S_ACS, scr + S_DT, scr + S_CB,
                                                  scr + S_XP, scr + S_YHP);
    // chunk states
    states_k<<<dim3(NH, NCH, 2), 256, 0, stream>>>(scr + S_ACS, scr + S_TT, scr + S_DT,
                                                   scr + S_XP, scr + S_ST);
    // recurrence over chunks
    recur_k<<<dim3(NH, 2), 256, 0, stream>>>(scr + S_ST, scr + S_TT, scr + S_SIN);
    // Y_off (+=)
    yoff_k<<<dim3(NH, NCH, 2), 256, 0, stream>>>(scr + S_ACS, scr + S_XP, scr + S_SIN,
                                                 scr + S_YHP);
    // gate + RMS norm (in place, + bf16 copy)
    gate_rms_k<<<4096, 256, 0, stream>>>(scr + S_YHP, scr + S_XP, scr + S_ZX, Dv, norm_w, yhp16);
    // out_proj: yout = yhp @ out_w^T   (4096 x 256, K=1024)
    gemm_bf16_k<<<dim3(2, 32, 1), 256, 0, stream>>>(
        yhp16, 1024, 0, outw16, 1024, 0, yout, 256, 0, 4096, 256, 1024, 0);
  }

  // r = [yf + t, yb_flip + t] (bf16); pr = r @ proj_w^T; out = x + pr^T + proj_b
  build_r_k<<<4096, 256, 0, stream>>>(ws + F_YF, ws + F_YB, ws + F_T, r16);
  gemm_bf16_k<<<dim3(2, 32, 1), 256, 0, stream>>>(
      r16, 512, 0, projw16, 512, 0, scr + S_PR, 256, 0, 4096, 256, 512, 0);
  final_add_k<<<512, 256, 0, stream>>>(x, scr + S_PR, proj_b, out);
}

// Round 3
// 644.510 us; speedup vs baseline: 2.0543x; 1.3659x over previous
//
#include <hip/hip_runtime.h>
#include <math.h>

namespace {

constexpr int NH    = 16;
constexpr int CONVD = 1280;
constexpr int DPROJ = 2320;
constexpr int NCH   = 8;

// workspace layout (in floats)
constexpr size_t F_STATS = 0;                 // 4: mu0,rstd0,mu1,rstd1
constexpr size_t F_PART  = 4;                 // 256: partial sums
constexpr size_t F_T     = 260;               // normalized transposed input (B,L,256)
constexpr size_t SZ_T    = 2ull * 2048 * 256; // 1048576
constexpr size_t F_YF    = F_T + SZ_T;
constexpr size_t F_YB    = F_YF + SZ_T;
constexpr size_t F_SCR   = F_YB + SZ_T;       // per-direction scratch (reused)

constexpr size_t S_ZX  = 0;                   // (B*L, 2320)
constexpr size_t SZ_ZX = 2ull * 2048 * 2320;  // 9502720
constexpr size_t S_XP  = S_ZX + SZ_ZX;        // (B*L, 1280) post-conv
constexpr size_t SZ_XP = 2ull * 2048 * 1280;  // 5242880
constexpr size_t S_DT  = S_XP + SZ_XP;        // (B*L,16)
constexpr size_t S_A   = S_DT + 65536;        // (B*L,16)
constexpr size_t S_ACS = S_A + 65536;         // (B*NCH*NH,256)
constexpr size_t S_TT  = S_ACS + 65536;       // (B*NCH*NH)
constexpr size_t S_CB  = S_TT + 256;          // (B*NCH,256,256)
constexpr size_t S_ST  = S_CB + 1048576;      // (B*NCH*NH, 64*128) fp32
constexpr size_t S_SIN = S_ST + 2097152;      // same
constexpr size_t S_YHP = S_SIN + 2097152;     // (B*L,1024)
constexpr size_t SZ_SCR = S_YHP + 4194304;
// overlays: yhp16 -> scr + S_ST (written by gate_rms, after recur_k done with S_ST)
//           r16   -> scr + S_ZX (after both directions)
constexpr size_t S_PR = S_ZX + 2097152;       // pr fp32 (B*L,256)
// persistent bf16 buffers appended after scratch:
constexpr size_t F_BF = F_SCR + SZ_SCR;       // ushort region base (as float offset)

typedef __bf16 bf16x8 __attribute__((ext_vector_type(8)));
typedef float  f32x4  __attribute__((ext_vector_type(4)));

__device__ __forceinline__ float silu(float v) { return v / (1.f + expf(-v)); }

__device__ __forceinline__ unsigned short f2bf(float f) {
  unsigned int u = __float_as_uint(f);
  return (unsigned short)((u + 0x7fffu + ((u >> 16) & 1u)) >> 16);
}
__device__ __forceinline__ float bf2f(unsigned short u) {
  return __uint_as_float((unsigned int)u << 16);
}

// ---------------- groupnorm stats ----------------
__global__ __launch_bounds__(256) void stats_partial_k(const float* __restrict__ x,
                                                       float* __restrict__ part) {
  int b = blockIdx.y, seg = blockIdx.x;
  const float4* base = (const float4*)(x + (size_t)b * 524288 + (size_t)seg * 8192);
  float s = 0.f, q = 0.f;
#pragma unroll
  for (int i = 0; i < 8; i++) {
    float4 v = base[threadIdx.x + i * 256];
    s += v.x + v.y + v.z + v.w;
    q += v.x * v.x + v.y * v.y + v.z * v.z + v.w * v.w;
  }
  for (int o = 32; o > 0; o >>= 1) { s += __shfl_down(s, o); q += __shfl_down(q, o); }
  __shared__ float ss[4], qq[4];
  int wid = threadIdx.x >> 6;
  if ((threadIdx.x & 63) == 0) { ss[wid] = s; qq[wid] = q; }
  __syncthreads();
  if (threadIdx.x == 0) {
    part[(b * 64 + seg) * 2]     = ss[0] + ss[1] + ss[2] + ss[3];
    part[(b * 64 + seg) * 2 + 1] = qq[0] + qq[1] + qq[2] + qq[3];
  }
}

__global__ __launch_bounds__(64) void stats_final_k(const float* __restrict__ part,
                                                    float* __restrict__ stats) {
  int b = blockIdx.x;
  float s = part[(b * 64 + threadIdx.x) * 2];
  float q = part[(b * 64 + threadIdx.x) * 2 + 1];
  for (int o = 32; o > 0; o >>= 1) { s += __shfl_down(s, o); q += __shfl_down(q, o); }
  if (threadIdx.x == 0) {
    float mu  = s / 524288.f;
    float var = q / 524288.f - mu * mu;
    stats[b * 2]     = mu;
    stats[b * 2 + 1] = rsqrtf(var + 1.1920929e-07f);
  }
}

// ---------------- normalize + transpose (fp32 + bf16 copies) ----------------
__global__ __launch_bounds__(256) void norm_t_k(const float* __restrict__ x,
                                                const float* __restrict__ gw,
                                                const float* __restrict__ gb,
                                                const float* __restrict__ stats,
                                                float* __restrict__ t,
                                                unsigned short* __restrict__ t16) {
  int row = blockIdx.x;            // b*2048 + l
  int b = row >> 11, l = row & 2047;
  int c = threadIdx.x;
  float mu = stats[b * 2], rstd = stats[b * 2 + 1];
  float v = x[(size_t)b * 524288 + (size_t)c * 2048 + l];
  float o = (v - mu) * rstd * gw[c] + gb[c];
  t[(size_t)row * 256 + c] = o;
  t16[(size_t)row * 256 + c] = f2bf(o);
}

// ---------------- generic fp32 -> bf16 convert ----------------
__global__ __launch_bounds__(256) void cvt_k(const float* __restrict__ in,
                                             unsigned short* __restrict__ out, int n4) {
  int i = blockIdx.x * 256 + threadIdx.x;
  if (i < n4) {
    float4 v = ((const float4*)in)[i];
    ushort4 o;
    o.x = f2bf(v.x); o.y = f2bf(v.y); o.z = f2bf(v.z); o.w = f2bf(v.w);
    ((ushort4*)out)[i] = o;
  }
}

// ---------------- bf16 MFMA GEMM: C(f32) = A(M,K) * B(N,K)^T ----------------
__global__ __launch_bounds__(256) void gemm_bf16_k(
    const unsigned short* __restrict__ A, int lda, long sA,
    const unsigned short* __restrict__ B, int ldb, long sB,
    float* __restrict__ C, int ldc, long sC,
    int M, int N, int K, int flip) {
  int zb = blockIdx.z;
  A += (size_t)zb * sA;
  B += (size_t)zb * sB;
  C += (size_t)zb * sC;
  int m0 = blockIdx.y * 128, n0 = blockIdx.x * 128;
  __shared__ unsigned short As[128][40];
  __shared__ unsigned short Bs[128][40];
  int tid = threadIdx.x;
  int lane = tid & 63, wid = tid >> 6;
  int wr = (wid >> 1) * 64, wc = (wid & 1) * 64;
  int fr = lane & 15, fq = lane >> 4;
  int sr = tid >> 2;
  int sk = (tid & 3) * 8;
  f32x4 acc[4][4] = {};
  for (int k0 = 0; k0 < K; k0 += 32) {
#pragma unroll
    for (int i = 0; i < 2; i++) {
      int r = sr + i * 64;
      int gm = (m0 + r) ^ flip;
      *(bf16x8*)&As[r][sk] = *(const bf16x8*)&A[(size_t)gm * lda + k0 + sk];
      int gn = n0 + r;
      if (gn >= N) gn = N - 1;
      *(bf16x8*)&Bs[r][sk] = *(const bf16x8*)&B[(size_t)gn * ldb + k0 + sk];
    }
    __syncthreads();
    bf16x8 a[4], b[4];
#pragma unroll
    for (int m = 0; m < 4; m++) a[m] = *(const bf16x8*)&As[wr + m * 16 + fr][fq * 8];
#pragma unroll
    for (int n = 0; n < 4; n++) b[n] = *(const bf16x8*)&Bs[wc + n * 16 + fr][fq * 8];
#pragma unroll
    for (int m = 0; m < 4; m++)
#pragma unroll
      for (int n = 0; n < 4; n++)
        acc[m][n] = __builtin_amdgcn_mfma_f32_16x16x32_bf16(a[m], b[n], acc[m][n], 0, 0, 0);
    __syncthreads();
  }
#pragma unroll
  for (int m = 0; m < 4; m++) {
    int row = m0 + wr + m * 16 + fq * 4;
#pragma unroll
    for (int n = 0; n < 4; n++) {
      int col = n0 + wc + n * 16 + fr;
      if (col < N) {
#pragma unroll
        for (int j = 0; j < 4; j++) C[(size_t)(row + j) * ldc + col] = acc[m][n][j];
      }
    }
  }
}

// ---------------- causal depthwise conv4 + silu ----------------
__global__ __launch_bounds__(256) void conv_k(const float* __restrict__ zx,
                                              const float* __restrict__ cw,
                                              const float* __restrict__ cb,
                                              float* __restrict__ xp) {
  int j = blockIdx.x * 256 + threadIdx.x;  // channel 0..1279
  int l = blockIdx.y, b = blockIdx.z;
  float acc = cb[j];
  size_t col = 1024 + j;
#pragma unroll
  for (int k = 0; k < 4; k++) {
    int ls = l - 3 + k;
    if (ls >= 0) acc += cw[j * 4 + k] * zx[(size_t)(b * 2048 + ls) * DPROJ + col];
  }
  xp[(size_t)(b * 2048 + l) * CONVD + j] = silu(acc);
}

// ---------------- bf16 copy of B/C section of xp ----------------
__global__ __launch_bounds__(256) void cvt_bc_k(const float* __restrict__ xp,
                                                unsigned short* __restrict__ bc16) {
  int row = blockIdx.x, c = threadIdx.x;
  bc16[(size_t)row * 256 + c] = f2bf(xp[(size_t)row * CONVD + 1024 + c]);
}

// ---------------- dt in fp32 (direct dot against t), A = -exp(A_log)*dt ----------------
__global__ __launch_bounds__(256) void dtg_k(const float* __restrict__ t,
                                             const float* __restrict__ in_w,
                                             const float* __restrict__ dtb,
                                             const float* __restrict__ Alog,
                                             float* __restrict__ dt,
                                             float* __restrict__ Ab, int flip) {
  int idx = blockIdx.x * 256 + threadIdx.x;  // 65536
  int row = idx >> 4, h = idx & 15;
  int ga = row ^ flip;
  const float4* t4 = (const float4*)(t + (size_t)ga * 256);
  const float4* w4 = (const float4*)(in_w + (size_t)(2304 + h) * 256);
  float s = 0.f;
#pragma unroll 8
  for (int k = 0; k < 64; k++) {
    float4 a = t4[k], b = w4[k];
    s += a.x * b.x + a.y * b.y + a.z * b.z + a.w * b.w;
  }
  float rawv = s + dtb[h];
  float d = (rawv > 20.f) ? rawv : log1pf(expf(rawv));
  dt[idx] = d;
  Ab[idx] = -expf(Alog[h]) * d;
}

// ---------------- per-chunk inclusive scan of A ----------------
__global__ __launch_bounds__(256) void scan_k(const float* __restrict__ Ab,
                                              float* __restrict__ Acs,
                                              float* __restrict__ Ttot) {
  int h = blockIdx.x, c = blockIdx.y, b = blockIdx.z;
  int l = threadIdx.x;
  __shared__ float buf0[256], buf1[256];
  buf0[l] = Ab[(size_t)(b * 2048 + c * 256 + l) * 16 + h];
  __syncthreads();
  float* src = buf0;
  float* dst = buf1;
  for (int off = 1; off < 256; off <<= 1) {
    float v = src[l];
    if (l >= off) v += src[l - off];
    dst[l] = v;
    __syncthreads();
    float* tmp = src; src = dst; dst = tmp;
  }
  float s = src[l];
  int chidx = (b * NCH + c) * NH + h;
  Acs[(size_t)chidx * 256 + l] = s;
  if (l == 255) Ttot[chidx] = s;
}

// ---------------- chunk states via MFMA: S[p=64][n=128] ----------------
__global__ __launch_bounds__(256) void states_mfma_k(
    const float* __restrict__ Acs, const float* __restrict__ Ttot,
    const float* __restrict__ dtb, const float* __restrict__ xp,
    const unsigned short* __restrict__ bc16, float* __restrict__ stout) {
  int h = blockIdx.x, c = blockIdx.y, b = blockIdx.z;
  int tid = threadIdx.x;
  int row0 = b * 2048 + c * 256;
  int chidx = (b * NCH + c) * NH + h;
  __shared__ float sXs[256];
  __shared__ unsigned short At[64][40];
  __shared__ unsigned short Bt[128][40];
  {
    float a = Acs[(size_t)chidx * 256 + tid];
    float Tt = Ttot[chidx];
    sXs[tid] = dtb[(size_t)(row0 + tid) * 16 + h] * __expf(Tt - a);
  }
  __syncthreads();
  int lane = tid & 63, w = tid >> 6;
  int fr = lane & 15, fq = lane >> 4;
  f32x4 acc[4][2] = {};
  for (int k0 = 0; k0 < 256; k0 += 32) {
#pragma unroll
    for (int i = 0; i < 8; i++) {
      int lin = tid + i * 256;
      int p = lin & 63, gl = lin >> 6;
      float v = xp[(size_t)(row0 + k0 + gl) * CONVD + h * 64 + p] * sXs[k0 + gl];
      At[p][gl] = f2bf(v);
    }
#pragma unroll
    for (int i = 0; i < 16; i++) {
      int lin = tid + i * 256;
      int n = lin & 127, gl = lin >> 7;
      Bt[n][gl] = bc16[(size_t)(row0 + k0 + gl) * 256 + n];
    }
    __syncthreads();
    bf16x8 a[4], bb[2];
#pragma unroll
    for (int m = 0; m < 4; m++) a[m] = *(const bf16x8*)&At[m * 16 + fr][fq * 8];
#pragma unroll
    for (int n = 0; n < 2; n++) bb[n] = *(const bf16x8*)&Bt[w * 32 + n * 16 + fr][fq * 8];
#pragma unroll
    for (int m = 0; m < 4; m++)
#pragma unroll
      for (int n = 0; n < 2; n++)
        acc[m][n] = __builtin_amdgcn_mfma_f32_16x16x32_bf16(a[m], bb[n], acc[m][n], 0, 0, 0);
    __syncthreads();
  }
#pragma unroll
  for (int m = 0; m < 4; m++) {
    int p = m * 16 + fq * 4;
#pragma unroll
    for (int n = 0; n < 2; n++) {
      int nn = w * 32 + n * 16 + fr;
#pragma unroll
      for (int j = 0; j < 4; j++)
        stout[(size_t)chidx * 8192 + (size_t)(p + j) * 128 + nn] = acc[m][n][j];
    }
  }
}

// ---------------- inter-chunk recurrence ----------------
__global__ __launch_bounds__(256) void recur_k(const float* __restrict__ st,
                                               const float* __restrict__ Ttot,
                                               float* __restrict__ Sin) {
  int h = blockIdx.x, b = blockIdx.y;
  int e0 = threadIdx.x * 32;
  float4 s[8];
#pragma unroll
  for (int j = 0; j < 8; j++) s[j] = make_float4(0.f, 0.f, 0.f, 0.f);
  for (int c = 0; c < 8; c++) {
    int chidx = (b * NCH + c) * NH + h;
    size_t base = (size_t)chidx * 8192 + e0;
    float4* so = (float4*)(Sin + base);
    const float4* si = (const float4*)(st + base);
    float dec = __expf(Ttot[chidx]);
#pragma unroll
    for (int j = 0; j < 8; j++) {
      so[j] = s[j];
      float4 v = si[j];
      s[j].x = s[j].x * dec + v.x; s[j].y = s[j].y * dec + v.y;
      s[j].z = s[j].z * dec + v.z; s[j].w = s[j].w * dec + v.w;
    }
  }
}

// ---------------- fused Y_diag + Y_off via MFMA ----------------
// Y[l=256][p=64] = [M | exp(A)*C] (256x384) @ [dtX ; Sin^T] (384x64)
__global__ __launch_bounds__(256) void ydo_k(
    const float* __restrict__ Acs, const float* __restrict__ dtb,
    const float* __restrict__ CB, const float* __restrict__ xp,
    const unsigned short* __restrict__ bc16, const float* __restrict__ Sin,
    float* __restrict__ yhp) {
  int h = blockIdx.x, c = blockIdx.y, b = blockIdx.z;
  int tid = threadIdx.x;
  int row0 = b * 2048 + c * 256;
  int chidx = (b * NCH + c) * NH + h;
  __shared__ float sA[256], sdt[256], sE[256];
  __shared__ unsigned short As[256][40];
  __shared__ unsigned short Bs[64][40];
  {
    float a = Acs[(size_t)chidx * 256 + tid];
    sA[tid] = a;
    sE[tid] = __expf(a);
    sdt[tid] = dtb[(size_t)(row0 + tid) * 16 + h];
  }
  __syncthreads();
  const float* CBb = CB + (size_t)(b * NCH + c) * 65536;
  const float* Sb  = Sin + (size_t)chidx * 8192;
  int lane = tid & 63, w = tid >> 6;
  int fr = lane & 15, fq = lane >> 4;
  f32x4 acc[4][4] = {};
  for (int kt = 0; kt < 12; kt++) {
    int k0 = kt * 32;
    if (kt < 8) {
      // A-tile: masked decay * CB
#pragma unroll
      for (int i = 0; i < 32; i++) {
        int lin = tid + i * 256;
        int kk = lin & 31, r = lin >> 5;
        int gk = k0 + kk;
        float v = (gk <= r) ? __expf(sA[r] - sA[gk]) * CBb[(size_t)r * 256 + gk] : 0.f;
        As[r][kk] = f2bf(v);
      }
      // B-tile: dt * x
#pragma unroll
      for (int i = 0; i < 8; i++) {
        int lin = tid + i * 256;
        int p = lin & 63, kk = lin >> 6;
        int gk = k0 + kk;
        float v = sdt[gk] * xp[(size_t)(row0 + gk) * CONVD + h * 64 + p];
        Bs[p][kk] = f2bf(v);
      }
    } else {
      int n0 = k0 - 256;  // 0..96
      // A-tile: exp(A[r]) * C[r][n]
#pragma unroll
      for (int i = 0; i < 32; i++) {
        int lin = tid + i * 256;
        int kk = lin & 31, r = lin >> 5;
        float cv = bf2f(bc16[(size_t)(row0 + r) * 256 + 128 + n0 + kk]);
        As[r][kk] = f2bf(sE[r] * cv);
      }
      // B-tile: Sin[p][n]
#pragma unroll
      for (int i = 0; i < 8; i++) {
        int lin = tid + i * 256;
        int kk = lin & 31, p = lin >> 5;
        Bs[p][kk] = f2bf(Sb[(size_t)p * 128 + n0 + kk]);
      }
    }
    __syncthreads();
    if (kt >= 8 || k0 <= w * 64 + 63) {  // skip fully-masked triangular tiles
      bf16x8 a[4], bb[4];
#pragma unroll
      for (int m = 0; m < 4; m++) a[m] = *(const bf16x8*)&As[w * 64 + m * 16 + fr][fq * 8];
#pragma unroll
      for (int n = 0; n < 4; n++) bb[n] = *(const bf16x8*)&Bs[n * 16 + fr][fq * 8];
#pragma unroll
      for (int m = 0; m < 4; m++)
#pragma unroll
        for (int n = 0; n < 4; n++)
          acc[m][n] = __builtin_amdgcn_mfma_f32_16x16x32_bf16(a[m], bb[n], acc[m][n], 0, 0, 0);
    }
    __syncthreads();
  }
#pragma unroll
  for (int m = 0; m < 4; m++) {
    int row = row0 + w * 64 + m * 16 + fq * 4;
#pragma unroll
    for (int n = 0; n < 4; n++) {
      int p = n * 16 + fr;
#pragma unroll
      for (int j = 0; j < 4; j++)
        yhp[(size_t)(row + j) * 1024 + h * 64 + p] = acc[m][n][j];
    }
  }
}

// ---------------- gate with silu(z), add x*D, RMS norm (+bf16 copy) ----------------
__global__ __launch_bounds__(256) void gate_rms_k(float* __restrict__ yhp,
                                                  const float* __restrict__ xp,
                                                  const float* __restrict__ zx,
                                                  const float* __restrict__ Dv,
                                                  const float* __restrict__ nw,
                                                  unsigned short* __restrict__ yhp16) {
  int row = blockIdx.x;
  float g[4];
  float ss = 0.f;
#pragma unroll
  for (int k = 0; k < 4; k++) {
    int i = threadIdx.x + k * 256;
    int h = i >> 6;
    float y = yhp[(size_t)row * 1024 + i] + xp[(size_t)row * CONVD + i] * Dv[h];
    float z = zx[(size_t)row * DPROJ + i];
    float gg = y * silu(z);
    ss += gg * gg;
    g[k] = gg;
  }
  for (int o = 32; o > 0; o >>= 1) ss += __shfl_down(ss, o);
  __shared__ float red[5];
  int wid = threadIdx.x >> 6;
  if ((threadIdx.x & 63) == 0) red[wid] = ss;
  __syncthreads();
  if (threadIdx.x == 0) red[4] = red[0] + red[1] + red[2] + red[3];
  __syncthreads();
  float rstd = rsqrtf(red[4] / 1024.f + 1e-5f);
#pragma unroll
  for (int k = 0; k < 4; k++) {
    int i = threadIdx.x + k * 256;
    float o = g[k] * rstd * nw[i];
    yhp[(size_t)row * 1024 + i] = o;
    yhp16[(size_t)row * 1024 + i] = f2bf(o);
  }
}

// ---------------- build r16 = bf16([yf + t, yb_flipped + t]) ----------------
__global__ __launch_bounds__(256) void build_r_k(const float* __restrict__ yf,
                                                 const float* __restrict__ yb,
                                                 const float* __restrict__ t,
                                                 unsigned short* __restrict__ r16) {
  int row = blockIdx.x;
  int c = threadIdx.x;
  float tv = t[(size_t)row * 256 + c];
  r16[(size_t)row * 512 + c]       = f2bf(yf[(size_t)row * 256 + c] + tv);
  r16[(size_t)row * 512 + 256 + c] = f2bf(yb[(size_t)(row ^ 2047) * 256 + c] + tv);
}

// ---------------- out = x + pr^T + proj_b ----------------
__global__ __launch_bounds__(256) void final_add_k(const float* __restrict__ x,
                                                   const float* __restrict__ pr,
                                                   const float* __restrict__ pb,
                                                   float* __restrict__ out) {
  int bc = blockIdx.x;  // b*256 + ch
  int b = bc >> 8, ch = bc & 255;
  float pbv = pb[ch];
#pragma unroll
  for (int i = 0; i < 8; i++) {
    int l = threadIdx.x + i * 256;
    size_t o = (size_t)b * 524288 + (size_t)ch * 2048 + l;
    out[o] = x[o] + pr[(size_t)(b * 2048 + l) * 256 + ch] + pbv;
  }
}

}  // namespace

extern "C" void kernel_launch(void* const* d_in, const int* in_sizes, int n_in,
                              void* d_out, int out_size, void* d_ws, size_t ws_size,
                              hipStream_t stream) {
  (void)in_sizes; (void)n_in; (void)out_size; (void)ws_size;
  const float* x      = (const float*)d_in[0];
  const float* gn_w   = (const float*)d_in[1];
  const float* gn_b   = (const float*)d_in[2];
  const float* proj_w = (const float*)d_in[3];
  const float* proj_b = (const float*)d_in[4];
  float* out = (float*)d_out;
  float* ws  = (float*)d_ws;
  float* scr = ws + F_SCR;

  unsigned short* t16     = (unsigned short*)(ws + F_BF);
  unsigned short* inw16   = t16 + 1048576;
  unsigned short* outw16  = inw16 + 593920;
  unsigned short* projw16 = outw16 + 262144;
  unsigned short* bc16    = projw16 + 131072;                // persistent now
  unsigned short* yhp16   = (unsigned short*)(scr + S_ST);   // overlay
  unsigned short* r16     = (unsigned short*)(scr + S_ZX);   // overlay (after dirs)

  // groupnorm + transpose (+bf16 t)
  stats_partial_k<<<dim3(64, 2), 256, 0, stream>>>(x, ws + F_PART);
  stats_final_k<<<2, 64, 0, stream>>>(ws + F_PART, ws + F_STATS);
  norm_t_k<<<4096, 256, 0, stream>>>(x, gn_w, gn_b, ws + F_STATS, ws + F_T, t16);
  cvt_k<<<(131072 / 4 + 255) / 256, 256, 0, stream>>>(proj_w, projw16, 131072 / 4);

  for (int dir = 0; dir < 2; dir++) {
    const float* in_w    = (const float*)d_in[5 + dir * 8];
    const float* conv_w  = (const float*)d_in[6 + dir * 8];
    const float* conv_b  = (const float*)d_in[7 + dir * 8];
    const float* dt_bias = (const float*)d_in[8 + dir * 8];
    const float* A_log   = (const float*)d_in[9 + dir * 8];
    const float* Dv      = (const float*)d_in[10 + dir * 8];
    const float* norm_w  = (const float*)d_in[11 + dir * 8];
    const float* out_w   = (const float*)d_in[12 + dir * 8];
    float* yout = ws + (dir ? F_YB : F_YF);
    int flip = dir ? 2047 : 0;

    cvt_k<<<(593920 / 4 + 255) / 256, 256, 0, stream>>>(in_w, inw16, 593920 / 4);
    cvt_k<<<(262144 / 4 + 255) / 256, 256, 0, stream>>>(out_w, outw16, 262144 / 4);

    // in_proj: zx = t(flip) @ in_w^T   (4096 x 2320, K=256)
    gemm_bf16_k<<<dim3(19, 32, 1), 256, 0, stream>>>(
        t16, 256, 0, inw16, 256, 0, scr + S_ZX, DPROJ, 0, 4096, DPROJ, 256, flip);
    // conv + silu
    conv_k<<<dim3(5, 2048, 2), 256, 0, stream>>>(scr + S_ZX, conv_w, conv_b, scr + S_XP);
    // bf16 copy of B/C
    cvt_bc_k<<<4096, 256, 0, stream>>>(scr + S_XP, bc16);
    // dt / A in fp32
    dtg_k<<<256, 256, 0, stream>>>(ws + F_T, in_w, dt_bias, A_log, scr + S_DT, scr + S_A, flip);
    // per-chunk scan
    scan_k<<<dim3(NH, NCH, 2), 256, 0, stream>>>(scr + S_A, scr + S_ACS, scr + S_TT);
    // CB = C @ B^T per (b,chunk): bf16 MFMA, 256x256, K=128
    gemm_bf16_k<<<dim3(2, 2, 16), 256, 0, stream>>>(
        bc16 + 128, 256, 65536L, bc16, 256, 65536L,
        scr + S_CB, 256, 65536L, 256, 256, 128, 0);
    // chunk states (MFMA)
    states_mfma_k<<<dim3(NH, NCH, 2), 256, 0, stream>>>(
        scr + S_ACS, scr + S_TT, scr + S_DT, scr + S_XP, bc16, scr + S_ST);
    // recurrence over chunks
    recur_k<<<dim3(NH, 2), 256, 0, stream>>>(scr + S_ST, scr + S_TT, scr + S_SIN);
    // fused Y_diag + Y_off (MFMA)
    ydo_k<<<dim3(NH, NCH, 2), 256, 0, stream>>>(
        scr + S_ACS, scr + S_DT, scr + S_CB, scr + S_XP, bc16, scr + S_SIN, scr + S_YHP);
    // gate + RMS norm (in place, + bf16 copy)
    gate_rms_k<<<4096, 256, 0, stream>>>(scr + S_YHP, scr + S_XP, scr + S_ZX, Dv, norm_w, yhp16);
    // out_proj: yout = yhp @ out_w^T   (4096 x 256, K=1024)
    gemm_bf16_k<<<dim3(2, 32, 1), 256, 0, stream>>>(
        yhp16, 1024, 0, outw16, 1024, 0, yout, 256, 0, 4096, 256, 1024, 0);
  }

  // r = [yf + t, yb_flip + t] (bf16); pr = r @ proj_w^T; out = x + pr^T + proj_b
  build_r_k<<<4096, 256, 0, stream>>>(ws + F_YF, ws + F_YB, ws + F_T, r16);
  gemm_bf16_k<<<dim3(2, 32, 1), 256, 0, stream>>>(
      r16, 512, 0, projw16, 512, 0, scr + S_PR, 256, 0, 4096, 256, 512, 0);
  final_add_k<<<512, 256, 0, stream>>>(x, scr + S_PR, proj_b, out);
}

// Round 4
// 475.420 us; speedup vs baseline: 2.7849x; 1.3557x over previous
//
#include <hip/hip_runtime.h>
#include <math.h>

namespace {

constexpr int NH    = 16;
constexpr int CONVD = 1280;
constexpr int DPROJ = 2320;
constexpr int NCH   = 8;

// workspace layout (in floats)
constexpr size_t F_STATS = 0;
constexpr size_t F_PART  = 4;
constexpr size_t F_T     = 260;
constexpr size_t SZ_T    = 2ull * 2048 * 256;
constexpr size_t F_YF    = F_T + SZ_T;
constexpr size_t F_YB    = F_YF + SZ_T;
constexpr size_t F_SCR   = F_YB + SZ_T;

constexpr size_t S_ZX  = 0;
constexpr size_t SZ_ZX = 2ull * 2048 * 2320;
constexpr size_t S_XP  = S_ZX + SZ_ZX;
constexpr size_t SZ_XP = 2ull * 2048 * 1280;
constexpr size_t S_DT  = S_XP + SZ_XP;
constexpr size_t S_A   = S_DT + 65536;
constexpr size_t S_ACS = S_A + 65536;
constexpr size_t S_TT  = S_ACS + 65536;
constexpr size_t S_CB  = S_TT + 256;          // (unused now, kept for layout)
constexpr size_t S_ST  = S_CB + 1048576;
constexpr size_t S_SIN = S_ST + 2097152;
constexpr size_t S_YHP = S_SIN + 2097152;
constexpr size_t SZ_SCR = S_YHP + 4194304;
constexpr size_t S_PR = S_ZX + 2097152;
constexpr size_t F_BF = F_SCR + SZ_SCR;

typedef __bf16 bf16x8 __attribute__((ext_vector_type(8)));
typedef float  f32x4  __attribute__((ext_vector_type(4)));

__device__ __forceinline__ float silu(float v) { return v / (1.f + expf(-v)); }

__device__ __forceinline__ unsigned short f2bf(float f) {
  unsigned int u = __float_as_uint(f);
  return (unsigned short)((u + 0x7fffu + ((u >> 16) & 1u)) >> 16);
}
__device__ __forceinline__ float bf2f(unsigned short u) {
  return __uint_as_float((unsigned int)u << 16);
}

// ---------------- groupnorm stats ----------------
__global__ __launch_bounds__(256) void stats_partial_k(const float* __restrict__ x,
                                                       float* __restrict__ part) {
  int b = blockIdx.y, seg = blockIdx.x;
  const float4* base = (const float4*)(x + (size_t)b * 524288 + (size_t)seg * 8192);
  float s = 0.f, q = 0.f;
#pragma unroll
  for (int i = 0; i < 8; i++) {
    float4 v = base[threadIdx.x + i * 256];
    s += v.x + v.y + v.z + v.w;
    q += v.x * v.x + v.y * v.y + v.z * v.z + v.w * v.w;
  }
  for (int o = 32; o > 0; o >>= 1) { s += __shfl_down(s, o); q += __shfl_down(q, o); }
  __shared__ float ss[4], qq[4];
  int wid = threadIdx.x >> 6;
  if ((threadIdx.x & 63) == 0) { ss[wid] = s; qq[wid] = q; }
  __syncthreads();
  if (threadIdx.x == 0) {
    part[(b * 64 + seg) * 2]     = ss[0] + ss[1] + ss[2] + ss[3];
    part[(b * 64 + seg) * 2 + 1] = qq[0] + qq[1] + qq[2] + qq[3];
  }
}

__global__ __launch_bounds__(64) void stats_final_k(const float* __restrict__ part,
                                                    float* __restrict__ stats) {
  int b = blockIdx.x;
  float s = part[(b * 64 + threadIdx.x) * 2];
  float q = part[(b * 64 + threadIdx.x) * 2 + 1];
  for (int o = 32; o > 0; o >>= 1) { s += __shfl_down(s, o); q += __shfl_down(q, o); }
  if (threadIdx.x == 0) {
    float mu  = s / 524288.f;
    float var = q / 524288.f - mu * mu;
    stats[b * 2]     = mu;
    stats[b * 2 + 1] = rsqrtf(var + 1.1920929e-07f);
  }
}

// ---------------- normalize + transpose ----------------
__global__ __launch_bounds__(256) void norm_t_k(const float* __restrict__ x,
                                                const float* __restrict__ gw,
                                                const float* __restrict__ gb,
                                                const float* __restrict__ stats,
                                                float* __restrict__ t,
                                                unsigned short* __restrict__ t16) {
  int row = blockIdx.x;
  int b = row >> 11, l = row & 2047;
  int c = threadIdx.x;
  float mu = stats[b * 2], rstd = stats[b * 2 + 1];
  float v = x[(size_t)b * 524288 + (size_t)c * 2048 + l];
  float o = (v - mu) * rstd * gw[c] + gb[c];
  t[(size_t)row * 256 + c] = o;
  t16[(size_t)row * 256 + c] = f2bf(o);
}

// ---------------- fp32 -> bf16 convert ----------------
__global__ __launch_bounds__(256) void cvt_k(const float* __restrict__ in,
                                             unsigned short* __restrict__ out, int n4) {
  int i = blockIdx.x * 256 + threadIdx.x;
  if (i < n4) {
    float4 v = ((const float4*)in)[i];
    ushort4 o;
    o.x = f2bf(v.x); o.y = f2bf(v.y); o.z = f2bf(v.z); o.w = f2bf(v.w);
    ((ushort4*)out)[i] = o;
  }
}

// ---------------- bf16 MFMA GEMM: C(f32) = A(M,K) * B(N,K)^T ----------------
__global__ __launch_bounds__(256) void gemm_bf16_k(
    const unsigned short* __restrict__ A, int lda, long sA,
    const unsigned short* __restrict__ B, int ldb, long sB,
    float* __restrict__ C, int ldc, long sC,
    int M, int N, int K, int flip) {
  int zb = blockIdx.z;
  A += (size_t)zb * sA;
  B += (size_t)zb * sB;
  C += (size_t)zb * sC;
  int m0 = blockIdx.y * 128, n0 = blockIdx.x * 128;
  __shared__ unsigned short As[128][40];
  __shared__ unsigned short Bs[128][40];
  int tid = threadIdx.x;
  int lane = tid & 63, wid = tid >> 6;
  int wr = (wid >> 1) * 64, wc = (wid & 1) * 64;
  int fr = lane & 15, fq = lane >> 4;
  int sr = tid >> 2;
  int sk = (tid & 3) * 8;
  f32x4 acc[4][4] = {};
  for (int k0 = 0; k0 < K; k0 += 32) {
#pragma unroll
    for (int i = 0; i < 2; i++) {
      int r = sr + i * 64;
      int gm = (m0 + r) ^ flip;
      *(bf16x8*)&As[r][sk] = *(const bf16x8*)&A[(size_t)gm * lda + k0 + sk];
      int gn = n0 + r;
      if (gn >= N) gn = N - 1;
      *(bf16x8*)&Bs[r][sk] = *(const bf16x8*)&B[(size_t)gn * ldb + k0 + sk];
    }
    __syncthreads();
    bf16x8 a[4], b[4];
#pragma unroll
    for (int m = 0; m < 4; m++) a[m] = *(const bf16x8*)&As[wr + m * 16 + fr][fq * 8];
#pragma unroll
    for (int n = 0; n < 4; n++) b[n] = *(const bf16x8*)&Bs[wc + n * 16 + fr][fq * 8];
#pragma unroll
    for (int m = 0; m < 4; m++)
#pragma unroll
      for (int n = 0; n < 4; n++)
        acc[m][n] = __builtin_amdgcn_mfma_f32_16x16x32_bf16(a[m], b[n], acc[m][n], 0, 0, 0);
    __syncthreads();
  }
#pragma unroll
  for (int m = 0; m < 4; m++) {
    int row = m0 + wr + m * 16 + fq * 4;
#pragma unroll
    for (int n = 0; n < 4; n++) {
      int col = n0 + wc + n * 16 + fr;
      if (col < N) {
#pragma unroll
        for (int j = 0; j < 4; j++) C[(size_t)(row + j) * ldc + col] = acc[m][n][j];
      }
    }
  }
}

// ---------------- causal depthwise conv4 + silu ----------------
__global__ __launch_bounds__(256) void conv_k(const float* __restrict__ zx,
                                              const float* __restrict__ cw,
                                              const float* __restrict__ cb,
                                              float* __restrict__ xp) {
  int j = blockIdx.x * 256 + threadIdx.x;
  int l = blockIdx.y, b = blockIdx.z;
  float acc = cb[j];
  size_t col = 1024 + j;
#pragma unroll
  for (int k = 0; k < 4; k++) {
    int ls = l - 3 + k;
    if (ls >= 0) acc += cw[j * 4 + k] * zx[(size_t)(b * 2048 + ls) * DPROJ + col];
  }
  xp[(size_t)(b * 2048 + l) * CONVD + j] = silu(acc);
}

// ---------------- bf16 copy of B/C section of xp ----------------
__global__ __launch_bounds__(256) void cvt_bc_k(const float* __restrict__ xp,
                                                unsigned short* __restrict__ bc16) {
  int row = blockIdx.x, c = threadIdx.x;
  bc16[(size_t)row * 256 + c] = f2bf(xp[(size_t)row * CONVD + 1024 + c]);
}

// ---------------- dt fp32, A = -exp(A_log)*dt ----------------
__global__ __launch_bounds__(256) void dtg_k(const float* __restrict__ t,
                                             const float* __restrict__ in_w,
                                             const float* __restrict__ dtb,
                                             const float* __restrict__ Alog,
                                             float* __restrict__ dt,
                                             float* __restrict__ Ab, int flip) {
  int idx = blockIdx.x * 256 + threadIdx.x;
  int row = idx >> 4, h = idx & 15;
  int ga = row ^ flip;
  const float4* t4 = (const float4*)(t + (size_t)ga * 256);
  const float4* w4 = (const float4*)(in_w + (size_t)(2304 + h) * 256);
  float s = 0.f;
#pragma unroll 8
  for (int k = 0; k < 64; k++) {
    float4 a = t4[k], b = w4[k];
    s += a.x * b.x + a.y * b.y + a.z * b.z + a.w * b.w;
  }
  float rawv = s + dtb[h];
  float d = (rawv > 20.f) ? rawv : log1pf(expf(rawv));
  dt[idx] = d;
  Ab[idx] = -expf(Alog[h]) * d;
}

// ---------------- per-chunk inclusive scan of A ----------------
__global__ __launch_bounds__(256) void scan_k(const float* __restrict__ Ab,
                                              float* __restrict__ Acs,
                                              float* __restrict__ Ttot) {
  int h = blockIdx.x, c = blockIdx.y, b = blockIdx.z;
  int l = threadIdx.x;
  __shared__ float buf0[256], buf1[256];
  buf0[l] = Ab[(size_t)(b * 2048 + c * 256 + l) * 16 + h];
  __syncthreads();
  float* src = buf0;
  float* dst = buf1;
  for (int off = 1; off < 256; off <<= 1) {
    float v = src[l];
    if (l >= off) v += src[l - off];
    dst[l] = v;
    __syncthreads();
    float* tmp = src; src = dst; dst = tmp;
  }
  float s = src[l];
  int chidx = (b * NCH + c) * NH + h;
  Acs[(size_t)chidx * 256 + l] = s;
  if (l == 255) Ttot[chidx] = s;
}

// ---------------- chunk states via MFMA: S[p=64][n-half=64] ----------------
__global__ __launch_bounds__(256) void states_mfma_k(
    const float* __restrict__ Acs, const float* __restrict__ Ttot,
    const float* __restrict__ dtb, const float* __restrict__ xp,
    const unsigned short* __restrict__ bc16, float* __restrict__ stout) {
  int h = blockIdx.x, c = blockIdx.y;
  int b = blockIdx.z >> 1, nh2 = blockIdx.z & 1;
  int tid = threadIdx.x;
  int row0 = b * 2048 + c * 256;
  int chidx = (b * NCH + c) * NH + h;
  __shared__ float sXs[256];
  __shared__ unsigned short At[64][40];
  __shared__ unsigned short Bt[64][40];
  {
    float a = Acs[(size_t)chidx * 256 + tid];
    float Tt = Ttot[chidx];
    sXs[tid] = dtb[(size_t)(row0 + tid) * 16 + h] * __expf(Tt - a);
  }
  __syncthreads();
  int lane = tid & 63, w = tid >> 6;
  int fr = lane & 15, fq = lane >> 4;
  f32x4 acc[4] = {};
  for (int k0 = 0; k0 < 256; k0 += 32) {
#pragma unroll
    for (int i = 0; i < 8; i++) {
      int lin = tid + i * 256;
      int p = lin & 63, gl = lin >> 6;
      float v = xp[(size_t)(row0 + k0 + gl) * CONVD + h * 64 + p] * sXs[k0 + gl];
      At[p][gl] = f2bf(v);
    }
#pragma unroll
    for (int i = 0; i < 8; i++) {
      int lin = tid + i * 256;
      int n = lin & 63, gl = lin >> 6;
      Bt[n][gl] = bc16[(size_t)(row0 + k0 + gl) * 256 + nh2 * 64 + n];
    }
    __syncthreads();
    bf16x8 bb = *(const bf16x8*)&Bt[w * 16 + fr][fq * 8];
#pragma unroll
    for (int m = 0; m < 4; m++) {
      bf16x8 a = *(const bf16x8*)&At[m * 16 + fr][fq * 8];
      acc[m] = __builtin_amdgcn_mfma_f32_16x16x32_bf16(a, bb, acc[m], 0, 0, 0);
    }
    __syncthreads();
  }
#pragma unroll
  for (int m = 0; m < 4; m++) {
    int p = m * 16 + fq * 4;
    int nn = nh2 * 64 + w * 16 + fr;
#pragma unroll
    for (int j = 0; j < 4; j++)
      stout[(size_t)chidx * 8192 + (size_t)(p + j) * 128 + nn] = acc[m][j];
  }
}

// ---------------- inter-chunk recurrence ----------------
__global__ __launch_bounds__(256) void recur_k(const float* __restrict__ st,
                                               const float* __restrict__ Ttot,
                                               float* __restrict__ Sin) {
  int h = blockIdx.x, b = blockIdx.y;
  int e0 = threadIdx.x * 32;
  float4 s[8];
#pragma unroll
  for (int j = 0; j < 8; j++) s[j] = make_float4(0.f, 0.f, 0.f, 0.f);
  for (int c = 0; c < 8; c++) {
    int chidx = (b * NCH + c) * NH + h;
    size_t base = (size_t)chidx * 8192 + e0;
    float4* so = (float4*)(Sin + base);
    const float4* si = (const float4*)(st + base);
    float dec = __expf(Ttot[chidx]);
#pragma unroll
    for (int j = 0; j < 8; j++) {
      so[j] = s[j];
      float4 v = si[j];
      s[j].x = s[j].x * dec + v.x; s[j].y = s[j].y * dec + v.y;
      s[j].z = s[j].z * dec + v.z; s[j].w = s[j].w * dec + v.w;
    }
  }
}

// ---------------- fused Y_diag + Y_off, flash-style, per (b,c,h,l-tile) ----------------
// Y[64 l x 64 p] = exp(A_l)*(C @ Sin^T) + sum_{s-tiles<=lt} (L o (C@B^T)) @ dtX
__global__ __launch_bounds__(256) void ydo2_k(
    const float* __restrict__ Acs, const float* __restrict__ dt,
    const unsigned short* __restrict__ bc16, const float* __restrict__ xp,
    const float* __restrict__ Sin, float* __restrict__ yhp) {
  int h = blockIdx.x;
  int cy = blockIdx.y;
  int c = cy >> 2, lt = cy & 3;
  int b = blockIdx.z;
  int tid = threadIdx.x;
  int lane = tid & 63, w = tid >> 6;
  int fr = lane & 15, fq = lane >> 4;
  int row0 = b * 2048 + c * 256;
  int chidx = (b * NCH + c) * NH + h;
  int l0 = lt * 64;

  __shared__ unsigned short sC[64][136];   // C tile (l x n128)
  __shared__ unsigned short sBS[64][136];  // Sin^T (p x n128), then B tiles (s x n128)
  __shared__ unsigned short sXt[64][72];   // dtX transposed (p x s64)
  __shared__ unsigned short sP[64][72];    // masked decay*CB (l x s64)
  __shared__ float sA[64], sAs[64];

  // stage C, Sin^T, sA
#pragma unroll
  for (int i = 0; i < 4; i++) {
    int chunk = tid + i * 256;            // 1024 chunks of 8 (64 rows x 16 chunks)
    int r = chunk >> 4, c8 = (chunk & 15) * 8;
    *(bf16x8*)&sC[r][c8] = *(const bf16x8*)&bc16[(size_t)(row0 + l0 + r) * 256 + 128 + c8];
  }
  const float* Sb = Sin + (size_t)chidx * 8192;
#pragma unroll
  for (int i = 0; i < 8; i++) {
    int chunk = tid + i * 256;            // 2048 float4 chunks (64 p x 32)
    int p = chunk >> 5, n4 = (chunk & 31) * 4;
    float4 v = *(const float4*)&Sb[(size_t)p * 128 + n4];
    ushort4 o;
    o.x = f2bf(v.x); o.y = f2bf(v.y); o.z = f2bf(v.z); o.w = f2bf(v.w);
    *(ushort4*)&sBS[p][n4] = o;
  }
  if (tid < 64) sA[tid] = Acs[(size_t)chidx * 256 + l0 + tid];
  __syncthreads();

  // C fragments (persist across all GEMMs)
  bf16x8 af[4];
#pragma unroll
  for (int k = 0; k < 4; k++) af[k] = *(const bf16x8*)&sC[w * 16 + fr][k * 32 + fq * 8];

  // off GEMM: acc[n(p)] = C @ Sin^T
  f32x4 acc[4] = {};
#pragma unroll
  for (int n = 0; n < 4; n++) {
#pragma unroll
    for (int k = 0; k < 4; k++) {
      bf16x8 bb = *(const bf16x8*)&sBS[n * 16 + fr][k * 32 + fq * 8];
      acc[n] = __builtin_amdgcn_mfma_f32_16x16x32_bf16(af[k], bb, acc[n], 0, 0, 0);
    }
  }
  // scale by exp(A_l)
  {
    int lrow = w * 16 + fq * 4;
    float el[4];
#pragma unroll
    for (int j = 0; j < 4; j++) el[j] = __expf(sA[lrow + j]);
#pragma unroll
    for (int n = 0; n < 4; n++)
#pragma unroll
      for (int j = 0; j < 4; j++) acc[n][j] *= el[j];
  }

  // diag s-tiles
  for (int st = 0; st <= lt; st++) {
    __syncthreads();  // protect sBS/sXt/sAs from previous iteration readers
    int srow0 = row0 + st * 64;
#pragma unroll
    for (int i = 0; i < 4; i++) {
      int chunk = tid + i * 256;
      int r = chunk >> 4, c8 = (chunk & 15) * 8;
      *(bf16x8*)&sBS[r][c8] = *(const bf16x8*)&bc16[(size_t)(srow0 + r) * 256 + c8];
    }
#pragma unroll
    for (int i = 0; i < 4; i++) {
      int chunk = tid + i * 256;          // 1024 float4 (64 s x 16 p4)
      int s = chunk >> 4, p4 = (chunk & 15) * 4;
      float dtv = dt[(size_t)(srow0 + s) * 16 + h];
      float4 v = *(const float4*)&xp[(size_t)(srow0 + s) * CONVD + h * 64 + p4];
      sXt[p4 + 0][s] = f2bf(v.x * dtv);
      sXt[p4 + 1][s] = f2bf(v.y * dtv);
      sXt[p4 + 2][s] = f2bf(v.z * dtv);
      sXt[p4 + 3][s] = f2bf(v.w * dtv);
    }
    if (tid < 64) sAs[tid] = Acs[(size_t)chidx * 256 + st * 64 + tid];
    __syncthreads();

    // CB = C @ B^T (64l x 64s per block; wave does 16 rows)
    f32x4 cb[4] = {};
#pragma unroll
    for (int n = 0; n < 4; n++) {
#pragma unroll
      for (int k = 0; k < 4; k++) {
        bf16x8 bb = *(const bf16x8*)&sBS[n * 16 + fr][k * 32 + fq * 8];
        cb[n] = __builtin_amdgcn_mfma_f32_16x16x32_bf16(af[k], bb, cb[n], 0, 0, 0);
      }
    }
    // decay + mask, write P bf16
    {
      int lrow = w * 16 + fq * 4;
      float al[4];
#pragma unroll
      for (int j = 0; j < 4; j++) al[j] = sA[lrow + j];
      bool full = (st < lt);
#pragma unroll
      for (int n = 0; n < 4; n++) {
        int srow = n * 16 + fr;
        float as_ = sAs[srow];
#pragma unroll
        for (int j = 0; j < 4; j++) {
          float v = (full || srow <= lrow + j) ? cb[n][j] * __expf(al[j] - as_) : 0.f;
          sP[lrow + j][srow] = f2bf(v);
        }
      }
    }
    // PV: acc += P @ dtX   (P rows are wave-private; intra-wave LDS dep handled by compiler)
#pragma unroll
    for (int k2 = 0; k2 < 2; k2++) {
      bf16x8 pa = *(const bf16x8*)&sP[w * 16 + fr][k2 * 32 + fq * 8];
#pragma unroll
      for (int n = 0; n < 4; n++) {
        bf16x8 bb = *(const bf16x8*)&sXt[n * 16 + fr][k2 * 32 + fq * 8];
        acc[n] = __builtin_amdgcn_mfma_f32_16x16x32_bf16(pa, bb, acc[n], 0, 0, 0);
      }
    }
  }

  // epilogue
#pragma unroll
  for (int n = 0; n < 4; n++) {
    int p = n * 16 + fr;
#pragma unroll
    for (int j = 0; j < 4; j++) {
      int row = row0 + l0 + w * 16 + fq * 4 + j;
      yhp[(size_t)row * 1024 + h * 64 + p] = acc[n][j];
    }
  }
}

// ---------------- gate with silu(z), add x*D, RMS norm (+bf16 copy) ----------------
__global__ __launch_bounds__(256) void gate_rms_k(float* __restrict__ yhp,
                                                  const float* __restrict__ xp,
                                                  const float* __restrict__ zx,
                                                  const float* __restrict__ Dv,
                                                  const float* __restrict__ nw,
                                                  unsigned short* __restrict__ yhp16) {
  int row = blockIdx.x;
  float g[4];
  float ss = 0.f;
#pragma unroll
  for (int k = 0; k < 4; k++) {
    int i = threadIdx.x + k * 256;
    int h = i >> 6;
    float y = yhp[(size_t)row * 1024 + i] + xp[(size_t)row * CONVD + i] * Dv[h];
    float z = zx[(size_t)row * DPROJ + i];
    float gg = y * silu(z);
    ss += gg * gg;
    g[k] = gg;
  }
  for (int o = 32; o > 0; o >>= 1) ss += __shfl_down(ss, o);
  __shared__ float red[5];
  int wid = threadIdx.x >> 6;
  if ((threadIdx.x & 63) == 0) red[wid] = ss;
  __syncthreads();
  if (threadIdx.x == 0) red[4] = red[0] + red[1] + red[2] + red[3];
  __syncthreads();
  float rstd = rsqrtf(red[4] / 1024.f + 1e-5f);
#pragma unroll
  for (int k = 0; k < 4; k++) {
    int i = threadIdx.x + k * 256;
    float o = g[k] * rstd * nw[i];
    yhp[(size_t)row * 1024 + i] = o;
    yhp16[(size_t)row * 1024 + i] = f2bf(o);
  }
}

// ---------------- build r16 ----------------
__global__ __launch_bounds__(256) void build_r_k(const float* __restrict__ yf,
                                                 const float* __restrict__ yb,
                                                 const float* __restrict__ t,
                                                 unsigned short* __restrict__ r16) {
  int row = blockIdx.x;
  int c = threadIdx.x;
  float tv = t[(size_t)row * 256 + c];
  r16[(size_t)row * 512 + c]       = f2bf(yf[(size_t)row * 256 + c] + tv);
  r16[(size_t)row * 512 + 256 + c] = f2bf(yb[(size_t)(row ^ 2047) * 256 + c] + tv);
}

// ---------------- out = x + pr^T + proj_b ----------------
__global__ __launch_bounds__(256) void final_add_k(const float* __restrict__ x,
                                                   const float* __restrict__ pr,
                                                   const float* __restrict__ pb,
                                                   float* __restrict__ out) {
  int bc = blockIdx.x;
  int b = bc >> 8, ch = bc & 255;
  float pbv = pb[ch];
#pragma unroll
  for (int i = 0; i < 8; i++) {
    int l = threadIdx.x + i * 256;
    size_t o = (size_t)b * 524288 + (size_t)ch * 2048 + l;
    out[o] = x[o] + pr[(size_t)(b * 2048 + l) * 256 + ch] + pbv;
  }
}

}  // namespace

extern "C" void kernel_launch(void* const* d_in, const int* in_sizes, int n_in,
                              void* d_out, int out_size, void* d_ws, size_t ws_size,
                              hipStream_t stream) {
  (void)in_sizes; (void)n_in; (void)out_size; (void)ws_size;
  const float* x      = (const float*)d_in[0];
  const float* gn_w   = (const float*)d_in[1];
  const float* gn_b   = (const float*)d_in[2];
  const float* proj_w = (const float*)d_in[3];
  const float* proj_b = (const float*)d_in[4];
  float* out = (float*)d_out;
  float* ws  = (float*)d_ws;
  float* scr = ws + F_SCR;

  unsigned short* t16     = (unsigned short*)(ws + F_BF);
  unsigned short* inw16   = t16 + 1048576;
  unsigned short* outw16  = inw16 + 593920;
  unsigned short* projw16 = outw16 + 262144;
  unsigned short* bc16    = projw16 + 131072;
  unsigned short* yhp16   = (unsigned short*)(scr + S_ST);
  unsigned short* r16     = (unsigned short*)(scr + S_ZX);

  stats_partial_k<<<dim3(64, 2), 256, 0, stream>>>(x, ws + F_PART);
  stats_final_k<<<2, 64, 0, stream>>>(ws + F_PART, ws + F_STATS);
  norm_t_k<<<4096, 256, 0, stream>>>(x, gn_w, gn_b, ws + F_STATS, ws + F_T, t16);
  cvt_k<<<(131072 / 4 + 255) / 256, 256, 0, stream>>>(proj_w, projw16, 131072 / 4);

  for (int dir = 0; dir < 2; dir++) {
    const float* in_w    = (const float*)d_in[5 + dir * 8];
    const float* conv_w  = (const float*)d_in[6 + dir * 8];
    const float* conv_b  = (const float*)d_in[7 + dir * 8];
    const float* dt_bias = (const float*)d_in[8 + dir * 8];
    const float* A_log   = (const float*)d_in[9 + dir * 8];
    const float* Dv      = (const float*)d_in[10 + dir * 8];
    const float* norm_w  = (const float*)d_in[11 + dir * 8];
    const float* out_w   = (const float*)d_in[12 + dir * 8];
    float* yout = ws + (dir ? F_YB : F_YF);
    int flip = dir ? 2047 : 0;

    cvt_k<<<(593920 / 4 + 255) / 256, 256, 0, stream>>>(in_w, inw16, 593920 / 4);
    cvt_k<<<(262144 / 4 + 255) / 256, 256, 0, stream>>>(out_w, outw16, 262144 / 4);

    // in_proj
    gemm_bf16_k<<<dim3(19, 32, 1), 256, 0, stream>>>(
        t16, 256, 0, inw16, 256, 0, scr + S_ZX, DPROJ, 0, 4096, DPROJ, 256, flip);
    // conv + silu
    conv_k<<<dim3(5, 2048, 2), 256, 0, stream>>>(scr + S_ZX, conv_w, conv_b, scr + S_XP);
    // bf16 copy of B/C
    cvt_bc_k<<<4096, 256, 0, stream>>>(scr + S_XP, bc16);
    // dt / A
    dtg_k<<<256, 256, 0, stream>>>(ws + F_T, in_w, dt_bias, A_log, scr + S_DT, scr + S_A, flip);
    // per-chunk scan
    scan_k<<<dim3(NH, NCH, 2), 256, 0, stream>>>(scr + S_A, scr + S_ACS, scr + S_TT);
    // chunk states (MFMA, n split x2)
    states_mfma_k<<<dim3(NH, NCH, 4), 256, 0, stream>>>(
        scr + S_ACS, scr + S_TT, scr + S_DT, scr + S_XP, bc16, scr + S_ST);
    // recurrence
    recur_k<<<dim3(NH, 2), 256, 0, stream>>>(scr + S_ST, scr + S_TT, scr + S_SIN);
    // fused Y_diag + Y_off, flash-style
    ydo2_k<<<dim3(NH, NCH * 4, 2), 256, 0, stream>>>(
        scr + S_ACS, scr + S_DT, bc16, scr + S_XP, scr + S_SIN, scr + S_YHP);
    // gate + RMS norm
    gate_rms_k<<<4096, 256, 0, stream>>>(scr + S_YHP, scr + S_XP, scr + S_ZX, Dv, norm_w, yhp16);
    // out_proj
    gemm_bf16_k<<<dim3(2, 32, 1), 256, 0, stream>>>(
        yhp16, 1024, 0, outw16, 1024, 0, yout, 256, 0, 4096, 256, 1024, 0);
  }

  build_r_k<<<4096, 256, 0, stream>>>(ws + F_YF, ws + F_YB, ws + F_T, r16);
  gemm_bf16_k<<<dim3(2, 32, 1), 256, 0, stream>>>(
      r16, 512, 0, projw16, 512, 0, scr + S_PR, 256, 0, 4096, 256, 512, 0);
  final_add_k<<<512, 256, 0, stream>>>(x, scr + S_PR, proj_b, out);
}

// Round 5
// 377.972 us; speedup vs baseline: 3.5029x; 1.2578x over previous
//
#include <hip/hip_runtime.h>
#include <math.h>

namespace {

constexpr int NH    = 16;
constexpr int CONVD = 1280;
constexpr int DPROJ = 2320;
constexpr int NCH   = 8;

// ---- workspace layout (float offsets) ----
constexpr size_t F_STATS = 0;                  // 4
constexpr size_t F_PART  = 4;                  // 256
constexpr size_t F_T     = 260;                // (B*L,256) fp32
constexpr size_t SZ_T    = 2ull * 2048 * 256;  // 1048576
constexpr size_t F_YF    = F_T + SZ_T;
constexpr size_t F_YB    = F_YF + SZ_T;
constexpr size_t F_SCR0  = F_YB + SZ_T;        // per-dir scratch base (x2)

// per-direction scratch (float offsets inside scr)
constexpr size_t S_ZX  = 0;                    // (B*L,2320) fp32
constexpr size_t S_XP  = 9502720;              // (B*L,1280) fp32
constexpr size_t S_DT  = S_XP + 5242880;       // (B*L,16)
constexpr size_t S_ACS = S_DT + 65536;         // (B*NCH*NH,256)
constexpr size_t S_TT  = S_ACS + 65536;        // 256
constexpr size_t S_ST  = S_TT + 256;           // chunk states fp32 (2097152)
constexpr size_t S_SIN = S_ST + 2097152;
constexpr size_t S_YHP = S_SIN + 2097152;      // (B*L,1024) fp32
constexpr size_t SZ_SCR = S_YHP + 4194304;     // 23,265,536 floats per dir

// overlays: yhp16 (ushort) -> scr + S_ST  (after recur_k done with S_ST)
//           r16   (ushort) -> scr0 + S_ZX (after gate_rms done with zx)
constexpr size_t S_PR = S_ZX + 1048576;        // pr fp32 (B*L,256) in scr0

constexpr size_t F_BF = F_SCR0 + 2 * SZ_SCR;   // bf16 (ushort) region base

typedef __bf16 bf16x8 __attribute__((ext_vector_type(8)));
typedef float  f32x4  __attribute__((ext_vector_type(4)));

__device__ __forceinline__ float silu(float v) { return v / (1.f + expf(-v)); }

__device__ __forceinline__ unsigned short f2bf(float f) {
  unsigned int u = __float_as_uint(f);
  return (unsigned short)((u + 0x7fffu + ((u >> 16) & 1u)) >> 16);
}

// ---------------- groupnorm stats ----------------
__global__ __launch_bounds__(256) void stats_partial_k(const float* __restrict__ x,
                                                       float* __restrict__ part) {
  int b = blockIdx.y, seg = blockIdx.x;
  const float4* base = (const float4*)(x + (size_t)b * 524288 + (size_t)seg * 8192);
  float s = 0.f, q = 0.f;
#pragma unroll
  for (int i = 0; i < 8; i++) {
    float4 v = base[threadIdx.x + i * 256];
    s += v.x + v.y + v.z + v.w;
    q += v.x * v.x + v.y * v.y + v.z * v.z + v.w * v.w;
  }
  for (int o = 32; o > 0; o >>= 1) { s += __shfl_down(s, o); q += __shfl_down(q, o); }
  __shared__ float ss[4], qq[4];
  int wid = threadIdx.x >> 6;
  if ((threadIdx.x & 63) == 0) { ss[wid] = s; qq[wid] = q; }
  __syncthreads();
  if (threadIdx.x == 0) {
    part[(b * 64 + seg) * 2]     = ss[0] + ss[1] + ss[2] + ss[3];
    part[(b * 64 + seg) * 2 + 1] = qq[0] + qq[1] + qq[2] + qq[3];
  }
}

__global__ __launch_bounds__(64) void stats_final_k(const float* __restrict__ part,
                                                    float* __restrict__ stats) {
  int b = blockIdx.x;
  float s = part[(b * 64 + threadIdx.x) * 2];
  float q = part[(b * 64 + threadIdx.x) * 2 + 1];
  for (int o = 32; o > 0; o >>= 1) { s += __shfl_down(s, o); q += __shfl_down(q, o); }
  if (threadIdx.x == 0) {
    float mu  = s / 524288.f;
    float var = q / 524288.f - mu * mu;
    stats[b * 2]     = mu;
    stats[b * 2 + 1] = rsqrtf(var + 1.1920929e-07f);
  }
}

// ---------------- normalize + transpose, LDS-tiled (coalesced both sides) ----------------
__global__ __launch_bounds__(256) void normt2_k(const float* __restrict__ x,
                                                const float* __restrict__ gw,
                                                const float* __restrict__ gb,
                                                const float* __restrict__ stats,
                                                float* __restrict__ t,
                                                unsigned short* __restrict__ t16) {
  int l0 = blockIdx.x * 32, c0 = blockIdx.y * 32, b = blockIdx.z;
  int tx = threadIdx.x & 31, ty = threadIdx.x >> 5;
  float mu = stats[b * 2], rstd = stats[b * 2 + 1];
  __shared__ float tile[32][33];
#pragma unroll
  for (int i = 0; i < 4; i++) {
    int c = c0 + ty + i * 8;
    float v = x[(size_t)b * 524288 + (size_t)c * 2048 + l0 + tx];
    tile[ty + i * 8][tx] = (v - mu) * rstd * gw[c] + gb[c];
  }
  __syncthreads();
#pragma unroll
  for (int i = 0; i < 4; i++) {
    int ll = ty + i * 8;
    size_t o = (size_t)(b * 2048 + l0 + ll) * 256 + c0 + tx;
    float v = tile[tx][ll];
    t[o] = v;
    t16[o] = f2bf(v);
  }
}

// ---------------- all weight tensors -> bf16, one launch ----------------
__global__ __launch_bounds__(256) void cvtw_k(
    const float* __restrict__ fiw, const float* __restrict__ biw,
    const float* __restrict__ fow, const float* __restrict__ bow,
    const float* __restrict__ pw,
    unsigned short* __restrict__ inw16, unsigned short* __restrict__ outw16,
    unsigned short* __restrict__ projw16) {
  int y = blockIdx.y;
  const float* src; unsigned short* dst; int n4;
  if (y == 0)      { src = fiw; dst = inw16;          n4 = 148480; }
  else if (y == 1) { src = biw; dst = inw16 + 593920; n4 = 148480; }
  else if (y == 2) { src = fow; dst = outw16;          n4 = 65536; }
  else if (y == 3) { src = bow; dst = outw16 + 262144; n4 = 65536; }
  else             { src = pw;  dst = projw16;         n4 = 32768; }
  int i = blockIdx.x * 256 + threadIdx.x;
  if (i < n4) {
    float4 v = ((const float4*)src)[i];
    ushort4 o;
    o.x = f2bf(v.x); o.y = f2bf(v.y); o.z = f2bf(v.z); o.w = f2bf(v.w);
    ((ushort4*)dst)[i] = o;
  }
}

// ---------------- bf16 MFMA GEMM: C(f32) = A(M,K) * B(N,K)^T (batched z) ----------------
__global__ __launch_bounds__(256) void gemm_bf16_k(
    const unsigned short* __restrict__ A, int lda, long sA,
    const unsigned short* __restrict__ B, int ldb, long sB,
    float* __restrict__ C, int ldc, long sC,
    int M, int N, int K, int flipsel) {
  int zb = blockIdx.z;
  A += (size_t)zb * sA;
  B += (size_t)zb * sB;
  C += (size_t)zb * sC;
  int flip = flipsel ? (zb ? 2047 : 0) : 0;
  int m0 = blockIdx.y * 128, n0 = blockIdx.x * 128;
  __shared__ unsigned short As[128][40];
  __shared__ unsigned short Bs[128][40];
  int tid = threadIdx.x;
  int lane = tid & 63, wid = tid >> 6;
  int wr = (wid >> 1) * 64, wc = (wid & 1) * 64;
  int fr = lane & 15, fq = lane >> 4;
  int sr = tid >> 2;
  int sk = (tid & 3) * 8;
  f32x4 acc[4][4] = {};
  for (int k0 = 0; k0 < K; k0 += 32) {
#pragma unroll
    for (int i = 0; i < 2; i++) {
      int r = sr + i * 64;
      int gm = (m0 + r) ^ flip;
      *(bf16x8*)&As[r][sk] = *(const bf16x8*)&A[(size_t)gm * lda + k0 + sk];
      int gn = n0 + r;
      if (gn >= N) gn = N - 1;
      *(bf16x8*)&Bs[r][sk] = *(const bf16x8*)&B[(size_t)gn * ldb + k0 + sk];
    }
    __syncthreads();
    bf16x8 a[4], b[4];
#pragma unroll
    for (int m = 0; m < 4; m++) a[m] = *(const bf16x8*)&As[wr + m * 16 + fr][fq * 8];
#pragma unroll
    for (int n = 0; n < 4; n++) b[n] = *(const bf16x8*)&Bs[wc + n * 16 + fr][fq * 8];
#pragma unroll
    for (int m = 0; m < 4; m++)
#pragma unroll
      for (int n = 0; n < 4; n++)
        acc[m][n] = __builtin_amdgcn_mfma_f32_16x16x32_bf16(a[m], b[n], acc[m][n], 0, 0, 0);
    __syncthreads();
  }
#pragma unroll
  for (int m = 0; m < 4; m++) {
    int row = m0 + wr + m * 16 + fq * 4;
#pragma unroll
    for (int n = 0; n < 4; n++) {
      int col = n0 + wc + n * 16 + fr;
      if (col < N) {
#pragma unroll
        for (int j = 0; j < 4; j++) C[(size_t)(row + j) * ldc + col] = acc[m][n][j];
      }
    }
  }
}

// ---------------- conv4 + silu + bc16 fold (both dirs) ----------------
__global__ __launch_bounds__(256) void conv2_k(
    const float* __restrict__ fcw, const float* __restrict__ bcw,
    const float* __restrict__ fcb, const float* __restrict__ bcb,
    float* __restrict__ scr0, long dstride, unsigned short* __restrict__ bc16_0) {
  int j = blockIdx.x * 256 + threadIdx.x;
  int l = blockIdx.y;
  int b = blockIdx.z & 1, dir = blockIdx.z >> 1;
  const float* cw = dir ? bcw : fcw;
  const float* cb = dir ? bcb : fcb;
  float* scr = scr0 + (size_t)dir * dstride;
  const float* zx = scr + S_ZX;
  float acc = cb[j];
  size_t col = 1024 + j;
#pragma unroll
  for (int k = 0; k < 4; k++) {
    int ls = l - 3 + k;
    if (ls >= 0) acc += cw[j * 4 + k] * zx[(size_t)(b * 2048 + ls) * DPROJ + col];
  }
  float o = silu(acc);
  int row = b * 2048 + l;
  (scr + S_XP)[(size_t)row * CONVD + j] = o;
  if (j >= 1024) (bc16_0 + (size_t)dir * 1048576)[(size_t)row * 256 + (j - 1024)] = f2bf(o);
}

// ---------------- fused dt (fp32 dot) + softplus + A + per-chunk scan ----------------
__global__ __launch_bounds__(256) void dscan_k(
    const float* __restrict__ t,
    const float* __restrict__ fiw, const float* __restrict__ biw,
    const float* __restrict__ fdtb, const float* __restrict__ bdtb,
    const float* __restrict__ fAlog, const float* __restrict__ bAlog,
    float* __restrict__ scr0, long dstride) {
  int h = blockIdx.x, c = blockIdx.y;
  int b = blockIdx.z & 1, dir = blockIdx.z >> 1;
  const float* in_w = dir ? biw : fiw;
  float dtbv = (dir ? bdtb : fdtb)[h];
  float alog = (dir ? bAlog : fAlog)[h];
  float* scr = scr0 + (size_t)dir * dstride;
  int l = threadIdx.x;
  int row = b * 2048 + c * 256 + l;
  int flip = dir ? 2047 : 0;
  __shared__ float sw[256];
  __shared__ float buf0[256], buf1[256];
  sw[l] = in_w[(size_t)(2304 + h) * 256 + l];
  __syncthreads();
  const float4* t4 = (const float4*)(t + (size_t)(row ^ flip) * 256);
  const float4* w4 = (const float4*)sw;
  float s = 0.f;
#pragma unroll 8
  for (int k = 0; k < 64; k++) {
    float4 a = t4[k], w = w4[k];
    s += a.x * w.x + a.y * w.y + a.z * w.z + a.w * w.w;
  }
  float rawv = s + dtbv;
  float d = (rawv > 20.f) ? rawv : log1pf(expf(rawv));
  (scr + S_DT)[(size_t)row * 16 + h] = d;
  buf0[l] = -expf(alog) * d;
  __syncthreads();
  float* src = buf0;
  float* dst = buf1;
  for (int off = 1; off < 256; off <<= 1) {
    float v = src[l];
    if (l >= off) v += src[l - off];
    dst[l] = v;
    __syncthreads();
    float* tmp = src; src = dst; dst = tmp;
  }
  float scn = src[l];
  int chidx = (b * NCH + c) * NH + h;
  (scr + S_ACS)[(size_t)chidx * 256 + l] = scn;
  if (l == 255) (scr + S_TT)[chidx] = scn;
}

// ---------------- chunk states via MFMA: S[p=64][n-half=64] ----------------
__global__ __launch_bounds__(256) void states_mfma_k(
    float* __restrict__ scr0, long dstride, const unsigned short* __restrict__ bc16_0) {
  int h = blockIdx.x, c = blockIdx.y;
  int nh2 = blockIdx.z & 1, b = (blockIdx.z >> 1) & 1, dir = blockIdx.z >> 2;
  float* scr = scr0 + (size_t)dir * dstride;
  const float* Acs = scr + S_ACS;
  const float* Ttot = scr + S_TT;
  const float* dtb = scr + S_DT;
  const float* xp = scr + S_XP;
  const unsigned short* bc16 = bc16_0 + (size_t)dir * 1048576;
  float* stout = scr + S_ST;
  int tid = threadIdx.x;
  int row0 = b * 2048 + c * 256;
  int chidx = (b * NCH + c) * NH + h;
  __shared__ float sXs[256];
  __shared__ unsigned short At[64][40];
  __shared__ unsigned short Bt[64][40];
  {
    float a = Acs[(size_t)chidx * 256 + tid];
    float Tt = Ttot[chidx];
    sXs[tid] = dtb[(size_t)(row0 + tid) * 16 + h] * __expf(Tt - a);
  }
  __syncthreads();
  int lane = tid & 63, w = tid >> 6;
  int fr = lane & 15, fq = lane >> 4;
  f32x4 acc[4] = {};
  for (int k0 = 0; k0 < 256; k0 += 32) {
#pragma unroll
    for (int i = 0; i < 8; i++) {
      int lin = tid + i * 256;
      int p = lin & 63, gl = lin >> 6;
      float v = xp[(size_t)(row0 + k0 + gl) * CONVD + h * 64 + p] * sXs[k0 + gl];
      At[p][gl] = f2bf(v);
    }
#pragma unroll
    for (int i = 0; i < 8; i++) {
      int lin = tid + i * 256;
      int n = lin & 63, gl = lin >> 6;
      Bt[n][gl] = bc16[(size_t)(row0 + k0 + gl) * 256 + nh2 * 64 + n];
    }
    __syncthreads();
    bf16x8 bb = *(const bf16x8*)&Bt[w * 16 + fr][fq * 8];
#pragma unroll
    for (int m = 0; m < 4; m++) {
      bf16x8 a = *(const bf16x8*)&At[m * 16 + fr][fq * 8];
      acc[m] = __builtin_amdgcn_mfma_f32_16x16x32_bf16(a, bb, acc[m], 0, 0, 0);
    }
    __syncthreads();
  }
#pragma unroll
  for (int m = 0; m < 4; m++) {
    int p = m * 16 + fq * 4;
    int nn = nh2 * 64 + w * 16 + fr;
#pragma unroll
    for (int j = 0; j < 4; j++)
      stout[(size_t)chidx * 8192 + (size_t)(p + j) * 128 + nn] = acc[m][j];
  }
}

// ---------------- inter-chunk recurrence ----------------
__global__ __launch_bounds__(256) void recur_k(float* __restrict__ scr0, long dstride) {
  int h = blockIdx.x;
  int b = blockIdx.y & 1, dir = blockIdx.y >> 1;
  float* scr = scr0 + (size_t)dir * dstride;
  const float* st = scr + S_ST;
  const float* Ttot = scr + S_TT;
  float* Sin = scr + S_SIN;
  int e0 = threadIdx.x * 32;
  float4 s[8];
#pragma unroll
  for (int j = 0; j < 8; j++) s[j] = make_float4(0.f, 0.f, 0.f, 0.f);
  for (int c = 0; c < 8; c++) {
    int chidx = (b * NCH + c) * NH + h;
    size_t base = (size_t)chidx * 8192 + e0;
    float4* so = (float4*)(Sin + base);
    const float4* si = (const float4*)(st + base);
    float dec = __expf(Ttot[chidx]);
#pragma unroll
    for (int j = 0; j < 8; j++) {
      so[j] = s[j];
      float4 v = si[j];
      s[j].x = s[j].x * dec + v.x; s[j].y = s[j].y * dec + v.y;
      s[j].z = s[j].z * dec + v.z; s[j].w = s[j].w * dec + v.w;
    }
  }
}

// ---------------- fused Y_diag + Y_off, flash-style ----------------
__global__ __launch_bounds__(256) void ydo2_k(
    float* __restrict__ scr0, long dstride, const unsigned short* __restrict__ bc16_0) {
  int h = blockIdx.x;
  int cy = blockIdx.y;
  int c = cy >> 2, lt = cy & 3;
  int b = blockIdx.z & 1, dir = blockIdx.z >> 1;
  float* scr = scr0 + (size_t)dir * dstride;
  const float* Acs = scr + S_ACS;
  const float* dt = scr + S_DT;
  const float* xp = scr + S_XP;
  const float* Sin = scr + S_SIN;
  float* yhp = scr + S_YHP;
  const unsigned short* bc16 = bc16_0 + (size_t)dir * 1048576;
  int tid = threadIdx.x;
  int lane = tid & 63, w = tid >> 6;
  int fr = lane & 15, fq = lane >> 4;
  int row0 = b * 2048 + c * 256;
  int chidx = (b * NCH + c) * NH + h;
  int l0 = lt * 64;

  __shared__ unsigned short sC[64][136];
  __shared__ unsigned short sBS[64][136];
  __shared__ unsigned short sXt[64][72];
  __shared__ unsigned short sP[64][72];
  __shared__ float sA[64], sAs[64];

#pragma unroll
  for (int i = 0; i < 4; i++) {
    int chunk = tid + i * 256;
    int r = chunk >> 4, c8 = (chunk & 15) * 8;
    *(bf16x8*)&sC[r][c8] = *(const bf16x8*)&bc16[(size_t)(row0 + l0 + r) * 256 + 128 + c8];
  }
  const float* Sb = Sin + (size_t)chidx * 8192;
#pragma unroll
  for (int i = 0; i < 8; i++) {
    int chunk = tid + i * 256;
    int p = chunk >> 5, n4 = (chunk & 31) * 4;
    float4 v = *(const float4*)&Sb[(size_t)p * 128 + n4];
    ushort4 o;
    o.x = f2bf(v.x); o.y = f2bf(v.y); o.z = f2bf(v.z); o.w = f2bf(v.w);
    *(ushort4*)&sBS[p][n4] = o;
  }
  if (tid < 64) sA[tid] = Acs[(size_t)chidx * 256 + l0 + tid];
  __syncthreads();

  bf16x8 af[4];
#pragma unroll
  for (int k = 0; k < 4; k++) af[k] = *(const bf16x8*)&sC[w * 16 + fr][k * 32 + fq * 8];

  f32x4 acc[4] = {};
#pragma unroll
  for (int n = 0; n < 4; n++) {
#pragma unroll
    for (int k = 0; k < 4; k++) {
      bf16x8 bb = *(const bf16x8*)&sBS[n * 16 + fr][k * 32 + fq * 8];
      acc[n] = __builtin_amdgcn_mfma_f32_16x16x32_bf16(af[k], bb, acc[n], 0, 0, 0);
    }
  }
  {
    int lrow = w * 16 + fq * 4;
    float el[4];
#pragma unroll
    for (int j = 0; j < 4; j++) el[j] = __expf(sA[lrow + j]);
#pragma unroll
    for (int n = 0; n < 4; n++)
#pragma unroll
      for (int j = 0; j < 4; j++) acc[n][j] *= el[j];
  }

  for (int st = 0; st <= lt; st++) {
    __syncthreads();
    int srow0 = row0 + st * 64;
#pragma unroll
    for (int i = 0; i < 4; i++) {
      int chunk = tid + i * 256;
      int r = chunk >> 4, c8 = (chunk & 15) * 8;
      *(bf16x8*)&sBS[r][c8] = *(const bf16x8*)&bc16[(size_t)(srow0 + r) * 256 + c8];
    }
#pragma unroll
    for (int i = 0; i < 4; i++) {
      int chunk = tid + i * 256;
      int s = chunk >> 4, p4 = (chunk & 15) * 4;
      float dtv = dt[(size_t)(srow0 + s) * 16 + h];
      float4 v = *(const float4*)&xp[(size_t)(srow0 + s) * CONVD + h * 64 + p4];
      sXt[p4 + 0][s] = f2bf(v.x * dtv);
      sXt[p4 + 1][s] = f2bf(v.y * dtv);
      sXt[p4 + 2][s] = f2bf(v.z * dtv);
      sXt[p4 + 3][s] = f2bf(v.w * dtv);
    }
    if (tid < 64) sAs[tid] = Acs[(size_t)chidx * 256 + st * 64 + tid];
    __syncthreads();

    f32x4 cb[4] = {};
#pragma unroll
    for (int n = 0; n < 4; n++) {
#pragma unroll
      for (int k = 0; k < 4; k++) {
        bf16x8 bb = *(const bf16x8*)&sBS[n * 16 + fr][k * 32 + fq * 8];
        cb[n] = __builtin_amdgcn_mfma_f32_16x16x32_bf16(af[k], bb, cb[n], 0, 0, 0);
      }
    }
    {
      int lrow = w * 16 + fq * 4;
      float al[4];
#pragma unroll
      for (int j = 0; j < 4; j++) al[j] = sA[lrow + j];
      bool full = (st < lt);
#pragma unroll
      for (int n = 0; n < 4; n++) {
        int srow = n * 16 + fr;
        float as_ = sAs[srow];
#pragma unroll
        for (int j = 0; j < 4; j++) {
          float v = (full || srow <= lrow + j) ? cb[n][j] * __expf(al[j] - as_) : 0.f;
          sP[lrow + j][srow] = f2bf(v);
        }
      }
    }
#pragma unroll
    for (int k2 = 0; k2 < 2; k2++) {
      bf16x8 pa = *(const bf16x8*)&sP[w * 16 + fr][k2 * 32 + fq * 8];
#pragma unroll
      for (int n = 0; n < 4; n++) {
        bf16x8 bb = *(const bf16x8*)&sXt[n * 16 + fr][k2 * 32 + fq * 8];
        acc[n] = __builtin_amdgcn_mfma_f32_16x16x32_bf16(pa, bb, acc[n], 0, 0, 0);
      }
    }
  }

#pragma unroll
  for (int n = 0; n < 4; n++) {
    int p = n * 16 + fr;
#pragma unroll
    for (int j = 0; j < 4; j++) {
      int row = row0 + l0 + w * 16 + fq * 4 + j;
      yhp[(size_t)row * 1024 + h * 64 + p] = acc[n][j];
    }
  }
}

// ---------------- gate + x*D + RMS norm (+bf16 copy), both dirs ----------------
__global__ __launch_bounds__(256) void gate_rms_k(
    float* __restrict__ scr0, long dstride,
    const float* __restrict__ fD, const float* __restrict__ bD,
    const float* __restrict__ fnw, const float* __restrict__ bnw) {
  int row = blockIdx.x;
  int dir = blockIdx.y;
  float* scr = scr0 + (size_t)dir * dstride;
  float* yhp = scr + S_YHP;
  const float* xp = scr + S_XP;
  const float* zx = scr + S_ZX;
  const float* Dv = dir ? bD : fD;
  const float* nw = dir ? bnw : fnw;
  unsigned short* yhp16 = (unsigned short*)(scr + S_ST);
  float g[4];
  float ss = 0.f;
#pragma unroll
  for (int k = 0; k < 4; k++) {
    int i = threadIdx.x + k * 256;
    int h = i >> 6;
    float y = yhp[(size_t)row * 1024 + i] + xp[(size_t)row * CONVD + i] * Dv[h];
    float z = zx[(size_t)row * DPROJ + i];
    float gg = y * silu(z);
    ss += gg * gg;
    g[k] = gg;
  }
  for (int o = 32; o > 0; o >>= 1) ss += __shfl_down(ss, o);
  __shared__ float red[5];
  int wid = threadIdx.x >> 6;
  if ((threadIdx.x & 63) == 0) red[wid] = ss;
  __syncthreads();
  if (threadIdx.x == 0) red[4] = red[0] + red[1] + red[2] + red[3];
  __syncthreads();
  float rstd = rsqrtf(red[4] / 1024.f + 1e-5f);
#pragma unroll
  for (int k = 0; k < 4; k++) {
    int i = threadIdx.x + k * 256;
    yhp16[(size_t)row * 1024 + i] = f2bf(g[k] * rstd * nw[i]);
  }
}

// ---------------- final proj GEMM with fused r-build in A staging ----------------
// pr(4096x256) = r(4096x512) @ proj_w^T ; r[:, :256]=yf+t, r[:,256:]=yb_flip+t
__global__ __launch_bounds__(256) void gemm_r_k(
    const float* __restrict__ yf, const float* __restrict__ yb,
    const float* __restrict__ t, const unsigned short* __restrict__ Bw,
    float* __restrict__ C) {
  int m0 = blockIdx.y * 128, n0 = blockIdx.x * 128;
  __shared__ unsigned short As[128][40];
  __shared__ unsigned short Bs[128][40];
  int tid = threadIdx.x;
  int lane = tid & 63, wid = tid >> 6;
  int wr = (wid >> 1) * 64, wc = (wid & 1) * 64;
  int fr = lane & 15, fq = lane >> 4;
  int sr = tid >> 2;
  int sk = (tid & 3) * 8;
  f32x4 acc[4][4] = {};
  for (int k0 = 0; k0 < 512; k0 += 32) {
#pragma unroll
    for (int i = 0; i < 2; i++) {
      int r = sr + i * 64;
      int gm = m0 + r;
      // build r on the fly: col k = k0+sk..k0+sk+7 (all within one half)
      const float* ybase;
      int cc;
      if (k0 < 256) { ybase = yf + (size_t)gm * 256; cc = k0 + sk; }
      else          { ybase = yb + (size_t)(gm ^ 2047) * 256; cc = k0 - 256 + sk; }
      const float* tbase = t + (size_t)gm * 256 + cc;
      unsigned short tmp[8];
#pragma unroll
      for (int q = 0; q < 8; q += 4) {
        float4 a = *(const float4*)(ybase + cc + q);
        float4 b = *(const float4*)(tbase + q);
        tmp[q + 0] = f2bf(a.x + b.x); tmp[q + 1] = f2bf(a.y + b.y);
        tmp[q + 2] = f2bf(a.z + b.z); tmp[q + 3] = f2bf(a.w + b.w);
      }
      *(ushort4*)&As[r][sk]     = *(ushort4*)&tmp[0];
      *(ushort4*)&As[r][sk + 4] = *(ushort4*)&tmp[4];
      int gn = n0 + r;
      if (gn >= 256) gn = 255;
      *(bf16x8*)&Bs[r][sk] = *(const bf16x8*)&Bw[(size_t)gn * 512 + k0 + sk];
    }
    __syncthreads();
    bf16x8 a[4], b[4];
#pragma unroll
    for (int m = 0; m < 4; m++) a[m] = *(const bf16x8*)&As[wr + m * 16 + fr][fq * 8];
#pragma unroll
    for (int n = 0; n < 4; n++) b[n] = *(const bf16x8*)&Bs[wc + n * 16 + fr][fq * 8];
#pragma unroll
    for (int m = 0; m < 4; m++)
#pragma unroll
      for (int n = 0; n < 4; n++)
        acc[m][n] = __builtin_amdgcn_mfma_f32_16x16x32_bf16(a[m], b[n], acc[m][n], 0, 0, 0);
    __syncthreads();
  }
#pragma unroll
  for (int m = 0; m < 4; m++) {
    int row = m0 + wr + m * 16 + fq * 4;
#pragma unroll
    for (int n = 0; n < 4; n++) {
      int col = n0 + wc + n * 16 + fr;
      if (col < 256) {
#pragma unroll
        for (int j = 0; j < 4; j++) C[(size_t)(row + j) * 256 + col] = acc[m][n][j];
      }
    }
  }
}

// ---------------- out = x + pr^T + proj_b, LDS-tiled transpose ----------------
__global__ __launch_bounds__(256) void final_add2_k(const float* __restrict__ x,
                                                    const float* __restrict__ pr,
                                                    const float* __restrict__ pb,
                                                    float* __restrict__ out) {
  int l0 = blockIdx.x * 32, c0 = blockIdx.y * 32, b = blockIdx.z;
  int tx = threadIdx.x & 31, ty = threadIdx.x >> 5;
  __shared__ float tile[32][33];
#pragma unroll
  for (int i = 0; i < 4; i++) {
    int ll = ty + i * 8;
    tile[ll][tx] = pr[(size_t)(b * 2048 + l0 + ll) * 256 + c0 + tx];
  }
  __syncthreads();
#pragma unroll
  for (int i = 0; i < 4; i++) {
    int ch = c0 + ty + i * 8;
    size_t o = (size_t)b * 524288 + (size_t)ch * 2048 + l0 + tx;
    out[o] = x[o] + tile[tx][ty + i * 8] + pb[ch];
  }
}

}  // namespace

extern "C" void kernel_launch(void* const* d_in, const int* in_sizes, int n_in,
                              void* d_out, int out_size, void* d_ws, size_t ws_size,
                              hipStream_t stream) {
  (void)in_sizes; (void)n_in; (void)out_size; (void)ws_size;
  const float* x      = (const float*)d_in[0];
  const float* gn_w   = (const float*)d_in[1];
  const float* gn_b   = (const float*)d_in[2];
  const float* proj_w = (const float*)d_in[3];
  const float* proj_b = (const float*)d_in[4];
  const float* fiw  = (const float*)d_in[5];
  const float* fcw  = (const float*)d_in[6];
  const float* fcb  = (const float*)d_in[7];
  const float* fdtb = (const float*)d_in[8];
  const float* fAl  = (const float*)d_in[9];
  const float* fD   = (const float*)d_in[10];
  const float* fnw  = (const float*)d_in[11];
  const float* fow  = (const float*)d_in[12];
  const float* biw  = (const float*)d_in[13];
  const float* bcw  = (const float*)d_in[14];
  const float* bcb  = (const float*)d_in[15];
  const float* bdtb = (const float*)d_in[16];
  const float* bAl  = (const float*)d_in[17];
  const float* bD   = (const float*)d_in[18];
  const float* bnw  = (const float*)d_in[19];
  const float* bow  = (const float*)d_in[20];
  float* out = (float*)d_out;
  float* ws  = (float*)d_ws;
  float* scr0 = ws + F_SCR0;
  const long DS = (long)SZ_SCR;

  unsigned short* t16     = (unsigned short*)(ws + F_BF);
  unsigned short* inw16   = t16 + 1048576;
  unsigned short* outw16  = inw16 + 1187840;
  unsigned short* projw16 = outw16 + 524288;
  unsigned short* bc16    = projw16 + 131072;
  unsigned short* yhp16   = (unsigned short*)(scr0 + S_ST);  // per-dir overlay (stride 2*DS ushorts)
  unsigned short* r16     = (unsigned short*)(scr0 + S_ZX);  // overlay after gate_rms
  float* pr = scr0 + S_PR;

  // groupnorm + transpose
  stats_partial_k<<<dim3(64, 2), 256, 0, stream>>>(x, ws + F_PART);
  stats_final_k<<<2, 64, 0, stream>>>(ws + F_PART, ws + F_STATS);
  normt2_k<<<dim3(64, 8, 2), 256, 0, stream>>>(x, gn_w, gn_b, ws + F_STATS, ws + F_T, t16);
  // weights -> bf16 (one launch)
  cvtw_k<<<dim3(580, 5), 256, 0, stream>>>(fiw, biw, fow, bow, proj_w, inw16, outw16, projw16);

  // in_proj, both dirs batched (flip per z)
  gemm_bf16_k<<<dim3(19, 32, 2), 256, 0, stream>>>(
      t16, 256, 0, inw16, 256, 593920L, scr0 + S_ZX, DPROJ, DS, 4096, DPROJ, 256, 1);
  // conv + silu + bc16
  conv2_k<<<dim3(5, 2048, 4), 256, 0, stream>>>(fcw, bcw, fcb, bcb, scr0, DS, bc16);
  // dt + scan
  dscan_k<<<dim3(NH, NCH, 4), 256, 0, stream>>>(
      ws + F_T, fiw, biw, fdtb, bdtb, fAl, bAl, scr0, DS);
  // chunk states
  states_mfma_k<<<dim3(NH, NCH, 8), 256, 0, stream>>>(scr0, DS, bc16);
  // inter-chunk recurrence
  recur_k<<<dim3(NH, 4), 256, 0, stream>>>(scr0, DS);
  // fused Y_diag + Y_off
  ydo2_k<<<dim3(NH, NCH * 4, 4), 256, 0, stream>>>(scr0, DS, bc16);
  // gate + RMS norm
  gate_rms_k<<<dim3(4096, 2), 256, 0, stream>>>(scr0, DS, fD, bD, fnw, bnw);
  // out_proj, both dirs batched
  gemm_bf16_k<<<dim3(2, 32, 2), 256, 0, stream>>>(
      yhp16, 1024, 2L * DS, outw16, 1024, 262144L, ws + F_YF, 256, (long)SZ_T,
      4096, 256, 1024, 0);
  // final proj with fused r-build
  gemm_r_k<<<dim3(2, 32, 1), 256, 0, stream>>>(ws + F_YF, ws + F_YB, ws + F_T, projw16, pr);
  // out = x + pr^T + proj_b
  final_add2_k<<<dim3(64, 8, 2), 256, 0, stream>>>(x, pr, proj_b, out);
  (void)r16;
}

// Round 6
// 344.749 us; speedup vs baseline: 3.8404x; 1.0964x over previous
//
#include <hip/hip_runtime.h>
#include <math.h>

namespace {

constexpr int NH    = 16;
constexpr int DPROJ = 2320;
constexpr int NCH   = 8;

// ---- workspace layout (float offsets) ----
constexpr size_t F_STATS = 0;                  // 4
constexpr size_t F_PART  = 4;                  // 256
constexpr size_t F_T     = 260;                // (B*L,256) fp32
constexpr size_t SZ_T    = 2ull * 2048 * 256;  // 1048576
constexpr size_t F_YF    = F_T + SZ_T;
constexpr size_t F_YB    = F_YF + SZ_T;
constexpr size_t F_PR    = F_YB + SZ_T;
constexpr size_t F_SCR0  = F_PR + SZ_T;        // per-dir scratch base (x2)

// per-direction scratch (float offsets inside scr); bf16 tensors cast to ushort*
constexpr size_t S_ZX16  = 0;                  // (B*L,2320) bf16 = 4,751,360 floats
constexpr size_t S_XP16  = 4751360;            // (B*L,1280) bf16 = 2,621,440 floats
constexpr size_t S_DT    = S_XP16 + 2621440;   // (B*L,16) fp32
constexpr size_t S_ACS   = S_DT + 65536;       // fp32
constexpr size_t S_TT    = S_ACS + 65536;      // 256 fp32
constexpr size_t S_ST    = S_TT + 256;         // 2097152 fp32
constexpr size_t S_SIN   = S_ST + 2097152;     // 2097152 fp32
constexpr size_t S_YHP16 = S_SIN + 2097152;    // (B*L,1024) bf16 = 2,097,152 floats
constexpr size_t SZ_SCR  = S_YHP16 + 2097152;  // 13,795,584 floats per dir

constexpr size_t F_BF = F_SCR0 + 2 * SZ_SCR;   // ushort region base (as float offset)

typedef __bf16 bf16x8 __attribute__((ext_vector_type(8)));
typedef float  f32x4  __attribute__((ext_vector_type(4)));

__device__ __forceinline__ float silu(float v) { return v / (1.f + expf(-v)); }

__device__ __forceinline__ unsigned short f2bf(float f) {
  unsigned int u = __float_as_uint(f);
  return (unsigned short)((u + 0x7fffu + ((u >> 16) & 1u)) >> 16);
}
__device__ __forceinline__ float bf2f(unsigned short u) {
  return __uint_as_float((unsigned int)u << 16);
}

// ---------------- groupnorm stats ----------------
__global__ __launch_bounds__(256) void stats_partial_k(const float* __restrict__ x,
                                                       float* __restrict__ part) {
  int b = blockIdx.y, seg = blockIdx.x;
  const float4* base = (const float4*)(x + (size_t)b * 524288 + (size_t)seg * 8192);
  float s = 0.f, q = 0.f;
#pragma unroll
  for (int i = 0; i < 8; i++) {
    float4 v = base[threadIdx.x + i * 256];
    s += v.x + v.y + v.z + v.w;
    q += v.x * v.x + v.y * v.y + v.z * v.z + v.w * v.w;
  }
  for (int o = 32; o > 0; o >>= 1) { s += __shfl_down(s, o); q += __shfl_down(q, o); }
  __shared__ float ss[4], qq[4];
  int wid = threadIdx.x >> 6;
  if ((threadIdx.x & 63) == 0) { ss[wid] = s; qq[wid] = q; }
  __syncthreads();
  if (threadIdx.x == 0) {
    part[(b * 64 + seg) * 2]     = ss[0] + ss[1] + ss[2] + ss[3];
    part[(b * 64 + seg) * 2 + 1] = qq[0] + qq[1] + qq[2] + qq[3];
  }
}

__global__ __launch_bounds__(64) void stats_final_k(const float* __restrict__ part,
                                                    float* __restrict__ stats) {
  int b = blockIdx.x;
  float s = part[(b * 64 + threadIdx.x) * 2];
  float q = part[(b * 64 + threadIdx.x) * 2 + 1];
  for (int o = 32; o > 0; o >>= 1) { s += __shfl_down(s, o); q += __shfl_down(q, o); }
  if (threadIdx.x == 0) {
    float mu  = s / 524288.f;
    float var = q / 524288.f - mu * mu;
    stats[b * 2]     = mu;
    stats[b * 2 + 1] = rsqrtf(var + 1.1920929e-07f);
  }
}

// ---------------- normalize + transpose, LDS-tiled ----------------
__global__ __launch_bounds__(256) void normt2_k(const float* __restrict__ x,
                                                const float* __restrict__ gw,
                                                const float* __restrict__ gb,
                                                const float* __restrict__ stats,
                                                float* __restrict__ t,
                                                unsigned short* __restrict__ t16) {
  int l0 = blockIdx.x * 32, c0 = blockIdx.y * 32, b = blockIdx.z;
  int tx = threadIdx.x & 31, ty = threadIdx.x >> 5;
  float mu = stats[b * 2], rstd = stats[b * 2 + 1];
  __shared__ float tile[32][33];
#pragma unroll
  for (int i = 0; i < 4; i++) {
    int c = c0 + ty + i * 8;
    float v = x[(size_t)b * 524288 + (size_t)c * 2048 + l0 + tx];
    tile[ty + i * 8][tx] = (v - mu) * rstd * gw[c] + gb[c];
  }
  __syncthreads();
#pragma unroll
  for (int i = 0; i < 4; i++) {
    int ll = ty + i * 8;
    size_t o = (size_t)(b * 2048 + l0 + ll) * 256 + c0 + tx;
    float v = tile[tx][ll];
    t[o] = v;
    t16[o] = f2bf(v);
  }
}

// ---------------- all weight tensors -> bf16 ----------------
__global__ __launch_bounds__(256) void cvtw_k(
    const float* __restrict__ fiw, const float* __restrict__ biw,
    const float* __restrict__ fow, const float* __restrict__ bow,
    const float* __restrict__ pw,
    unsigned short* __restrict__ inw16, unsigned short* __restrict__ outw16,
    unsigned short* __restrict__ projw16) {
  int y = blockIdx.y;
  const float* src; unsigned short* dst; int n4;
  if (y == 0)      { src = fiw; dst = inw16;          n4 = 148480; }
  else if (y == 1) { src = biw; dst = inw16 + 593920; n4 = 148480; }
  else if (y == 2) { src = fow; dst = outw16;          n4 = 65536; }
  else if (y == 3) { src = bow; dst = outw16 + 262144; n4 = 65536; }
  else             { src = pw;  dst = projw16;         n4 = 32768; }
  int i = blockIdx.x * 256 + threadIdx.x;
  if (i < n4) {
    float4 v = ((const float4*)src)[i];
    ushort4 o;
    o.x = f2bf(v.x); o.y = f2bf(v.y); o.z = f2bf(v.z); o.w = f2bf(v.w);
    ((ushort4*)dst)[i] = o;
  }
}

// ---------------- bf16 MFMA GEMM: C = A(M,K)*B(N,K)^T; C fp32 or bf16 ----------------
__global__ __launch_bounds__(256) void gemm_bf16_k(
    const unsigned short* __restrict__ A, int lda, long sA,
    const unsigned short* __restrict__ B, int ldb, long sB,
    void* __restrict__ Cout, int ldc, long sC,
    int M, int N, int K, int flipsel, int obf) {
  int zb = blockIdx.z;
  A += (size_t)zb * sA;
  B += (size_t)zb * sB;
  int flip = flipsel ? (zb ? 2047 : 0) : 0;
  int m0 = blockIdx.y * 128, n0 = blockIdx.x * 128;
  __shared__ unsigned short As[128][40];
  __shared__ unsigned short Bs[128][40];
  int tid = threadIdx.x;
  int lane = tid & 63, wid = tid >> 6;
  int wr = (wid >> 1) * 64, wc = (wid & 1) * 64;
  int fr = lane & 15, fq = lane >> 4;
  int sr = tid >> 2;
  int sk = (tid & 3) * 8;
  f32x4 acc[4][4] = {};
  for (int k0 = 0; k0 < K; k0 += 32) {
#pragma unroll
    for (int i = 0; i < 2; i++) {
      int r = sr + i * 64;
      int gm = (m0 + r) ^ flip;
      *(bf16x8*)&As[r][sk] = *(const bf16x8*)&A[(size_t)gm * lda + k0 + sk];
      int gn = n0 + r;
      if (gn >= N) gn = N - 1;
      *(bf16x8*)&Bs[r][sk] = *(const bf16x8*)&B[(size_t)gn * ldb + k0 + sk];
    }
    __syncthreads();
    bf16x8 a[4], b[4];
#pragma unroll
    for (int m = 0; m < 4; m++) a[m] = *(const bf16x8*)&As[wr + m * 16 + fr][fq * 8];
#pragma unroll
    for (int n = 0; n < 4; n++) b[n] = *(const bf16x8*)&Bs[wc + n * 16 + fr][fq * 8];
#pragma unroll
    for (int m = 0; m < 4; m++)
#pragma unroll
      for (int n = 0; n < 4; n++)
        acc[m][n] = __builtin_amdgcn_mfma_f32_16x16x32_bf16(a[m], b[n], acc[m][n], 0, 0, 0);
    __syncthreads();
  }
  if (obf) {
    unsigned short* C16 = (unsigned short*)Cout + (size_t)zb * sC;
#pragma unroll
    for (int m = 0; m < 4; m++) {
      int row = m0 + wr + m * 16 + fq * 4;
#pragma unroll
      for (int n = 0; n < 4; n++) {
        int col = n0 + wc + n * 16 + fr;
        if (col < N) {
#pragma unroll
          for (int j = 0; j < 4; j++) C16[(size_t)(row + j) * ldc + col] = f2bf(acc[m][n][j]);
        }
      }
    }
  } else {
    float* C = (float*)Cout + (size_t)zb * sC;
#pragma unroll
    for (int m = 0; m < 4; m++) {
      int row = m0 + wr + m * 16 + fq * 4;
#pragma unroll
      for (int n = 0; n < 4; n++) {
        int col = n0 + wc + n * 16 + fr;
        if (col < N) {
#pragma unroll
          for (int j = 0; j < 4; j++) C[(size_t)(row + j) * ldc + col] = acc[m][n][j];
        }
      }
    }
  }
}

// ---------------- conv4 + silu, sliding-window, bf16 in/out ----------------
__global__ __launch_bounds__(256) void conv3_k(
    const float* __restrict__ fcw, const float* __restrict__ bcw,
    const float* __restrict__ fcb, const float* __restrict__ bcb,
    float* __restrict__ scr0, long DS) {
  int j = blockIdx.x * 256 + threadIdx.x;      // channel 0..1279
  int l0 = blockIdx.y * 64;
  int b = blockIdx.z & 1, dir = blockIdx.z >> 1;
  float* scr = scr0 + (size_t)dir * DS;
  const unsigned short* zx16 = (const unsigned short*)(scr + S_ZX16);
  unsigned short* xp16 = (unsigned short*)(scr + S_XP16);
  const float* cwp = (dir ? bcw : fcw) + j * 4;
  float c0 = cwp[0], c1 = cwp[1], c2 = cwp[2], c3 = cwp[3];
  float cb = (dir ? bcb : fcb)[j];
  size_t colz = 1024 + j;
  float w0 = 0.f, w1 = 0.f, w2 = 0.f;
  if (l0 >= 3) {
    w0 = bf2f(zx16[(size_t)(b * 2048 + l0 - 3) * DPROJ + colz]);
    w1 = bf2f(zx16[(size_t)(b * 2048 + l0 - 2) * DPROJ + colz]);
    w2 = bf2f(zx16[(size_t)(b * 2048 + l0 - 1) * DPROJ + colz]);
  }
  for (int l = l0; l < l0 + 64; l++) {
    float cur = bf2f(zx16[(size_t)(b * 2048 + l) * DPROJ + colz]);
    float o = cb + c0 * w0 + c1 * w1 + c2 * w2 + c3 * cur;
    xp16[(size_t)(b * 2048 + l) * 1280 + j] = f2bf(silu(o));
    w0 = w1; w1 = w2; w2 = cur;
  }
}

// ---------------- fused dt (fp32 dot) + softplus + A + per-chunk scan ----------------
__global__ __launch_bounds__(256) void dscan_k(
    const float* __restrict__ t,
    const float* __restrict__ fiw, const float* __restrict__ biw,
    const float* __restrict__ fdtb, const float* __restrict__ bdtb,
    const float* __restrict__ fAlog, const float* __restrict__ bAlog,
    float* __restrict__ scr0, long DS) {
  int h = blockIdx.x, c = blockIdx.y;
  int b = blockIdx.z & 1, dir = blockIdx.z >> 1;
  const float* in_w = dir ? biw : fiw;
  float dtbv = (dir ? bdtb : fdtb)[h];
  float alog = (dir ? bAlog : fAlog)[h];
  float* scr = scr0 + (size_t)dir * DS;
  int l = threadIdx.x;
  int row = b * 2048 + c * 256 + l;
  int flip = dir ? 2047 : 0;
  __shared__ float sw[256];
  __shared__ float buf0[256], buf1[256];
  sw[l] = in_w[(size_t)(2304 + h) * 256 + l];
  __syncthreads();
  const float4* t4 = (const float4*)(t + (size_t)(row ^ flip) * 256);
  const float4* w4 = (const float4*)sw;
  float s = 0.f;
#pragma unroll 8
  for (int k = 0; k < 64; k++) {
    float4 a = t4[k], w = w4[k];
    s += a.x * w.x + a.y * w.y + a.z * w.z + a.w * w.w;
  }
  float rawv = s + dtbv;
  float d = (rawv > 20.f) ? rawv : log1pf(expf(rawv));
  (scr + S_DT)[(size_t)row * 16 + h] = d;
  buf0[l] = -expf(alog) * d;
  __syncthreads();
  float* src = buf0;
  float* dst = buf1;
  for (int off = 1; off < 256; off <<= 1) {
    float v = src[l];
    if (l >= off) v += src[l - off];
    dst[l] = v;
    __syncthreads();
    float* tmp = src; src = dst; dst = tmp;
  }
  float scn = src[l];
  int chidx = (b * NCH + c) * NH + h;
  (scr + S_ACS)[(size_t)chidx * 256 + l] = scn;
  if (l == 255) (scr + S_TT)[chidx] = scn;
}

// ---------------- chunk states via MFMA: S[p=64][n-half=64] ----------------
__global__ __launch_bounds__(256) void states_mfma_k(float* __restrict__ scr0, long DS) {
  int h = blockIdx.x, c = blockIdx.y;
  int nh2 = blockIdx.z & 1, b = (blockIdx.z >> 1) & 1, dir = blockIdx.z >> 2;
  float* scr = scr0 + (size_t)dir * DS;
  const float* Acs = scr + S_ACS;
  const float* Ttot = scr + S_TT;
  const float* dtb = scr + S_DT;
  const unsigned short* xp16 = (const unsigned short*)(scr + S_XP16);
  float* stout = scr + S_ST;
  int tid = threadIdx.x;
  int row0 = b * 2048 + c * 256;
  int chidx = (b * NCH + c) * NH + h;
  __shared__ float sXs[256];
  __shared__ unsigned short At[64][40];
  __shared__ unsigned short Bt[64][40];
  {
    float a = Acs[(size_t)chidx * 256 + tid];
    float Tt = Ttot[chidx];
    sXs[tid] = dtb[(size_t)(row0 + tid) * 16 + h] * __expf(Tt - a);
  }
  __syncthreads();
  int lane = tid & 63, w = tid >> 6;
  int fr = lane & 15, fq = lane >> 4;
  f32x4 acc[4] = {};
  for (int k0 = 0; k0 < 256; k0 += 32) {
#pragma unroll
    for (int i = 0; i < 8; i++) {
      int lin = tid + i * 256;
      int p = lin & 63, gl = lin >> 6;
      float v = bf2f(xp16[(size_t)(row0 + k0 + gl) * 1280 + h * 64 + p]) * sXs[k0 + gl];
      At[p][gl] = f2bf(v);
    }
#pragma unroll
    for (int i = 0; i < 8; i++) {
      int lin = tid + i * 256;
      int n = lin & 63, gl = lin >> 6;
      Bt[n][gl] = xp16[(size_t)(row0 + k0 + gl) * 1280 + 1024 + nh2 * 64 + n];
    }
    __syncthreads();
    bf16x8 bb = *(const bf16x8*)&Bt[w * 16 + fr][fq * 8];
#pragma unroll
    for (int m = 0; m < 4; m++) {
      bf16x8 a = *(const bf16x8*)&At[m * 16 + fr][fq * 8];
      acc[m] = __builtin_amdgcn_mfma_f32_16x16x32_bf16(a, bb, acc[m], 0, 0, 0);
    }
    __syncthreads();
  }
#pragma unroll
  for (int m = 0; m < 4; m++) {
    int p = m * 16 + fq * 4;
    int nn = nh2 * 64 + w * 16 + fr;
#pragma unroll
    for (int j = 0; j < 4; j++)
      stout[(size_t)chidx * 8192 + (size_t)(p + j) * 128 + nn] = acc[m][j];
  }
}

// ---------------- inter-chunk recurrence ----------------
__global__ __launch_bounds__(256) void recur_k(float* __restrict__ scr0, long DS) {
  int h = blockIdx.x;
  int b = blockIdx.y & 1, dir = blockIdx.y >> 1;
  float* scr = scr0 + (size_t)dir * DS;
  const float* st = scr + S_ST;
  const float* Ttot = scr + S_TT;
  float* Sin = scr + S_SIN;
  int e0 = threadIdx.x * 32;
  float4 s[8];
#pragma unroll
  for (int j = 0; j < 8; j++) s[j] = make_float4(0.f, 0.f, 0.f, 0.f);
  for (int c = 0; c < 8; c++) {
    int chidx = (b * NCH + c) * NH + h;
    size_t base = (size_t)chidx * 8192 + e0;
    float4* so = (float4*)(Sin + base);
    const float4* si = (const float4*)(st + base);
    float dec = __expf(Ttot[chidx]);
#pragma unroll
    for (int j = 0; j < 8; j++) {
      so[j] = s[j];
      float4 v = si[j];
      s[j].x = s[j].x * dec + v.x; s[j].y = s[j].y * dec + v.y;
      s[j].z = s[j].z * dec + v.z; s[j].w = s[j].w * dec + v.w;
    }
  }
}

// ---------------- fused Y_diag + Y_off, flash-style, bf16 out ----------------
__global__ __launch_bounds__(256) void ydo2_k(float* __restrict__ scr0, long DS) {
  int h = blockIdx.x;
  int cy = blockIdx.y;
  int c = cy >> 2, lt = cy & 3;
  int b = blockIdx.z & 1, dir = blockIdx.z >> 1;
  float* scr = scr0 + (size_t)dir * DS;
  const float* Acs = scr + S_ACS;
  const float* dt = scr + S_DT;
  const unsigned short* xp16 = (const unsigned short*)(scr + S_XP16);
  const float* Sin = scr + S_SIN;
  unsigned short* yhp16 = (unsigned short*)(scr + S_YHP16);
  int tid = threadIdx.x;
  int lane = tid & 63, w = tid >> 6;
  int fr = lane & 15, fq = lane >> 4;
  int row0 = b * 2048 + c * 256;
  int chidx = (b * NCH + c) * NH + h;
  int l0 = lt * 64;

  __shared__ unsigned short sC[64][136];
  __shared__ unsigned short sBS[64][136];
  __shared__ unsigned short sXt[64][72];
  __shared__ unsigned short sP[64][72];
  __shared__ float sA[64], sAs[64];

#pragma unroll
  for (int i = 0; i < 4; i++) {
    int chunk = tid + i * 256;
    int r = chunk >> 4, c8 = (chunk & 15) * 8;
    *(bf16x8*)&sC[r][c8] = *(const bf16x8*)&xp16[(size_t)(row0 + l0 + r) * 1280 + 1152 + c8];
  }
  const float* Sb = Sin + (size_t)chidx * 8192;
#pragma unroll
  for (int i = 0; i < 8; i++) {
    int chunk = tid + i * 256;
    int p = chunk >> 5, n4 = (chunk & 31) * 4;
    float4 v = *(const float4*)&Sb[(size_t)p * 128 + n4];
    ushort4 o;
    o.x = f2bf(v.x); o.y = f2bf(v.y); o.z = f2bf(v.z); o.w = f2bf(v.w);
    *(ushort4*)&sBS[p][n4] = o;
  }
  if (tid < 64) sA[tid] = Acs[(size_t)chidx * 256 + l0 + tid];
  __syncthreads();

  bf16x8 af[4];
#pragma unroll
  for (int k = 0; k < 4; k++) af[k] = *(const bf16x8*)&sC[w * 16 + fr][k * 32 + fq * 8];

  f32x4 acc[4] = {};
#pragma unroll
  for (int n = 0; n < 4; n++) {
#pragma unroll
    for (int k = 0; k < 4; k++) {
      bf16x8 bb = *(const bf16x8*)&sBS[n * 16 + fr][k * 32 + fq * 8];
      acc[n] = __builtin_amdgcn_mfma_f32_16x16x32_bf16(af[k], bb, acc[n], 0, 0, 0);
    }
  }
  {
    int lrow = w * 16 + fq * 4;
    float el[4];
#pragma unroll
    for (int j = 0; j < 4; j++) el[j] = __expf(sA[lrow + j]);
#pragma unroll
    for (int n = 0; n < 4; n++)
#pragma unroll
      for (int j = 0; j < 4; j++) acc[n][j] *= el[j];
  }

  for (int st = 0; st <= lt; st++) {
    __syncthreads();
    int srow0 = row0 + st * 64;
#pragma unroll
    for (int i = 0; i < 4; i++) {
      int chunk = tid + i * 256;
      int r = chunk >> 4, c8 = (chunk & 15) * 8;
      *(bf16x8*)&sBS[r][c8] = *(const bf16x8*)&xp16[(size_t)(srow0 + r) * 1280 + 1024 + c8];
    }
#pragma unroll
    for (int i = 0; i < 4; i++) {
      int chunk = tid + i * 256;
      int s = chunk >> 4, p4 = (chunk & 15) * 4;
      float dtv = dt[(size_t)(srow0 + s) * 16 + h];
      ushort4 ux = *(const ushort4*)&xp16[(size_t)(srow0 + s) * 1280 + h * 64 + p4];
      sXt[p4 + 0][s] = f2bf(bf2f(ux.x) * dtv);
      sXt[p4 + 1][s] = f2bf(bf2f(ux.y) * dtv);
      sXt[p4 + 2][s] = f2bf(bf2f(ux.z) * dtv);
      sXt[p4 + 3][s] = f2bf(bf2f(ux.w) * dtv);
    }
    if (tid < 64) sAs[tid] = Acs[(size_t)chidx * 256 + st * 64 + tid];
    __syncthreads();

    f32x4 cb[4] = {};
#pragma unroll
    for (int n = 0; n < 4; n++) {
#pragma unroll
      for (int k = 0; k < 4; k++) {
        bf16x8 bb = *(const bf16x8*)&sBS[n * 16 + fr][k * 32 + fq * 8];
        cb[n] = __builtin_amdgcn_mfma_f32_16x16x32_bf16(af[k], bb, cb[n], 0, 0, 0);
      }
    }
    {
      int lrow = w * 16 + fq * 4;
      float al[4];
#pragma unroll
      for (int j = 0; j < 4; j++) al[j] = sA[lrow + j];
      bool full = (st < lt);
#pragma unroll
      for (int n = 0; n < 4; n++) {
        int srow = n * 16 + fr;
        float as_ = sAs[srow];
#pragma unroll
        for (int j = 0; j < 4; j++) {
          float v = (full || srow <= lrow + j) ? cb[n][j] * __expf(al[j] - as_) : 0.f;
          sP[lrow + j][srow] = f2bf(v);
        }
      }
    }
#pragma unroll
    for (int k2 = 0; k2 < 2; k2++) {
      bf16x8 pa = *(const bf16x8*)&sP[w * 16 + fr][k2 * 32 + fq * 8];
#pragma unroll
      for (int n = 0; n < 4; n++) {
        bf16x8 bb = *(const bf16x8*)&sXt[n * 16 + fr][k2 * 32 + fq * 8];
        acc[n] = __builtin_amdgcn_mfma_f32_16x16x32_bf16(pa, bb, acc[n], 0, 0, 0);
      }
    }
  }

#pragma unroll
  for (int n = 0; n < 4; n++) {
    int p = n * 16 + fr;
#pragma unroll
    for (int j = 0; j < 4; j++) {
      int row = row0 + l0 + w * 16 + fq * 4 + j;
      yhp16[(size_t)row * 1024 + h * 64 + p] = f2bf(acc[n][j]);
    }
  }
}

// ---------------- gate + x*D + RMS norm, all bf16, in place ----------------
__global__ __launch_bounds__(256) void gate_rms_k(
    float* __restrict__ scr0, long DS,
    const float* __restrict__ fD, const float* __restrict__ bD,
    const float* __restrict__ fnw, const float* __restrict__ bnw) {
  int row = blockIdx.x;
  int dir = blockIdx.y;
  float* scr = scr0 + (size_t)dir * DS;
  unsigned short* yhp16 = (unsigned short*)(scr + S_YHP16);
  const unsigned short* xp16 = (const unsigned short*)(scr + S_XP16);
  const unsigned short* zx16 = (const unsigned short*)(scr + S_ZX16);
  const float* Dv = dir ? bD : fD;
  const float* nw = dir ? bnw : fnw;
  float g[4];
  float ss = 0.f;
#pragma unroll
  for (int k = 0; k < 4; k++) {
    int i = threadIdx.x + k * 256;
    int h = i >> 6;
    float y = bf2f(yhp16[(size_t)row * 1024 + i]) +
              bf2f(xp16[(size_t)row * 1280 + i]) * Dv[h];
    float z = bf2f(zx16[(size_t)row * DPROJ + i]);
    float gg = y * silu(z);
    ss += gg * gg;
    g[k] = gg;
  }
  for (int o = 32; o > 0; o >>= 1) ss += __shfl_down(ss, o);
  __shared__ float red[5];
  int wid = threadIdx.x >> 6;
  if ((threadIdx.x & 63) == 0) red[wid] = ss;
  __syncthreads();
  if (threadIdx.x == 0) red[4] = red[0] + red[1] + red[2] + red[3];
  __syncthreads();
  float rstd = rsqrtf(red[4] / 1024.f + 1e-5f);
#pragma unroll
  for (int k = 0; k < 4; k++) {
    int i = threadIdx.x + k * 256;
    yhp16[(size_t)row * 1024 + i] = f2bf(g[k] * rstd * nw[i]);
  }
}

// ---------------- final proj GEMM with fused r-build ----------------
__global__ __launch_bounds__(256) void gemm_r_k(
    const float* __restrict__ yf, const float* __restrict__ yb,
    const float* __restrict__ t, const unsigned short* __restrict__ Bw,
    float* __restrict__ C) {
  int m0 = blockIdx.y * 128, n0 = blockIdx.x * 128;
  __shared__ unsigned short As[128][40];
  __shared__ unsigned short Bs[128][40];
  int tid = threadIdx.x;
  int lane = tid & 63, wid = tid >> 6;
  int wr = (wid >> 1) * 64, wc = (wid & 1) * 64;
  int fr = lane & 15, fq = lane >> 4;
  int sr = tid >> 2;
  int sk = (tid & 3) * 8;
  f32x4 acc[4][4] = {};
  for (int k0 = 0; k0 < 512; k0 += 32) {
#pragma unroll
    for (int i = 0; i < 2; i++) {
      int r = sr + i * 64;
      int gm = m0 + r;
      const float* ybase;
      int cc;
      if (k0 < 256) { ybase = yf + (size_t)gm * 256; cc = k0 + sk; }
      else          { ybase = yb + (size_t)(gm ^ 2047) * 256; cc = k0 - 256 + sk; }
      const float* tbase = t + (size_t)gm * 256 + cc;
      unsigned short tmp[8];
#pragma unroll
      for (int q = 0; q < 8; q += 4) {
        float4 a = *(const float4*)(ybase + cc + q);
        float4 b = *(const float4*)(tbase + q);
        tmp[q + 0] = f2bf(a.x + b.x); tmp[q + 1] = f2bf(a.y + b.y);
        tmp[q + 2] = f2bf(a.z + b.z); tmp[q + 3] = f2bf(a.w + b.w);
      }
      *(ushort4*)&As[r][sk]     = *(ushort4*)&tmp[0];
      *(ushort4*)&As[r][sk + 4] = *(ushort4*)&tmp[4];
      int gn = n0 + r;
      if (gn >= 256) gn = 255;
      *(bf16x8*)&Bs[r][sk] = *(const bf16x8*)&Bw[(size_t)gn * 512 + k0 + sk];
    }
    __syncthreads();
    bf16x8 a[4], b[4];
#pragma unroll
    for (int m = 0; m < 4; m++) a[m] = *(const bf16x8*)&As[wr + m * 16 + fr][fq * 8];
#pragma unroll
    for (int n = 0; n < 4; n++) b[n] = *(const bf16x8*)&Bs[wc + n * 16 + fr][fq * 8];
#pragma unroll
    for (int m = 0; m < 4; m++)
#pragma unroll
      for (int n = 0; n < 4; n++)
        acc[m][n] = __builtin_amdgcn_mfma_f32_16x16x32_bf16(a[m], b[n], acc[m][n], 0, 0, 0);
    __syncthreads();
  }
#pragma unroll
  for (int m = 0; m < 4; m++) {
    int row = m0 + wr + m * 16 + fq * 4;
#pragma unroll
    for (int n = 0; n < 4; n++) {
      int col = n0 + wc + n * 16 + fr;
      if (col < 256) {
#pragma unroll
        for (int j = 0; j < 4; j++) C[(size_t)(row + j) * 256 + col] = acc[m][n][j];
      }
    }
  }
}

// ---------------- out = x + pr^T + proj_b, LDS-tiled transpose ----------------
__global__ __launch_bounds__(256) void final_add2_k(const float* __restrict__ x,
                                                    const float* __restrict__ pr,
                                                    const float* __restrict__ pb,
                                                    float* __restrict__ out) {
  int l0 = blockIdx.x * 32, c0 = blockIdx.y * 32, b = blockIdx.z;
  int tx = threadIdx.x & 31, ty = threadIdx.x >> 5;
  __shared__ float tile[32][33];
#pragma unroll
  for (int i = 0; i < 4; i++) {
    int ll = ty + i * 8;
    tile[ll][tx] = pr[(size_t)(b * 2048 + l0 + ll) * 256 + c0 + tx];
  }
  __syncthreads();
#pragma unroll
  for (int i = 0; i < 4; i++) {
    int ch = c0 + ty + i * 8;
    size_t o = (size_t)b * 524288 + (size_t)ch * 2048 + l0 + tx;
    out[o] = x[o] + tile[tx][ty + i * 8] + pb[ch];
  }
}

}  // namespace

extern "C" void kernel_launch(void* const* d_in, const int* in_sizes, int n_in,
                              void* d_out, int out_size, void* d_ws, size_t ws_size,
                              hipStream_t stream) {
  (void)in_sizes; (void)n_in; (void)out_size; (void)ws_size;
  const float* x      = (const float*)d_in[0];
  const float* gn_w   = (const float*)d_in[1];
  const float* gn_b   = (const float*)d_in[2];
  const float* proj_w = (const float*)d_in[3];
  const float* proj_b = (const float*)d_in[4];
  const float* fiw  = (const float*)d_in[5];
  const float* fcw  = (const float*)d_in[6];
  const float* fcb  = (const float*)d_in[7];
  const float* fdtb = (const float*)d_in[8];
  const float* fAl  = (const float*)d_in[9];
  const float* fD   = (const float*)d_in[10];
  const float* fnw  = (const float*)d_in[11];
  const float* fow  = (const float*)d_in[12];
  const float* biw  = (const float*)d_in[13];
  const float* bcw  = (const float*)d_in[14];
  const float* bcb  = (const float*)d_in[15];
  const float* bdtb = (const float*)d_in[16];
  const float* bAl  = (const float*)d_in[17];
  const float* bD   = (const float*)d_in[18];
  const float* bnw  = (const float*)d_in[19];
  const float* bow  = (const float*)d_in[20];
  float* out = (float*)d_out;
  float* ws  = (float*)d_ws;
  float* scr0 = ws + F_SCR0;
  const long DS = (long)SZ_SCR;          // per-dir stride in floats
  const long DSU = DS * 2;               // per-dir stride in ushorts

  unsigned short* t16     = (unsigned short*)(ws + F_BF);
  unsigned short* inw16   = t16 + 1048576;
  unsigned short* outw16  = inw16 + 1187840;
  unsigned short* projw16 = outw16 + 524288;
  unsigned short* zx16    = (unsigned short*)(scr0 + S_ZX16);
  unsigned short* yhp16   = (unsigned short*)(scr0 + S_YHP16);
  float* pr = ws + F_PR;

  // groupnorm + transpose
  stats_partial_k<<<dim3(64, 2), 256, 0, stream>>>(x, ws + F_PART);
  stats_final_k<<<2, 64, 0, stream>>>(ws + F_PART, ws + F_STATS);
  normt2_k<<<dim3(64, 8, 2), 256, 0, stream>>>(x, gn_w, gn_b, ws + F_STATS, ws + F_T, t16);
  // weights -> bf16
  cvtw_k<<<dim3(580, 5), 256, 0, stream>>>(fiw, biw, fow, bow, proj_w, inw16, outw16, projw16);

  // in_proj (bf16 out), both dirs batched
  gemm_bf16_k<<<dim3(19, 32, 2), 256, 0, stream>>>(
      t16, 256, 0, inw16, 256, 593920L, zx16, DPROJ, DSU, 4096, DPROJ, 256, 1, 1);
  // conv + silu (sliding window, bf16)
  conv3_k<<<dim3(5, 32, 4), 256, 0, stream>>>(fcw, bcw, fcb, bcb, scr0, DS);
  // dt + scan (fp32)
  dscan_k<<<dim3(NH, NCH, 4), 256, 0, stream>>>(
      ws + F_T, fiw, biw, fdtb, bdtb, fAl, bAl, scr0, DS);
  // chunk states
  states_mfma_k<<<dim3(NH, NCH, 8), 256, 0, stream>>>(scr0, DS);
  // inter-chunk recurrence
  recur_k<<<dim3(NH, 4), 256, 0, stream>>>(scr0, DS);
  // fused Y_diag + Y_off
  ydo2_k<<<dim3(NH, NCH * 4, 4), 256, 0, stream>>>(scr0, DS);
  // gate + RMS norm (in place on yhp16)
  gate_rms_k<<<dim3(4096, 2), 256, 0, stream>>>(scr0, DS, fD, bD, fnw, bnw);
  // out_proj (fp32 out), both dirs batched
  gemm_bf16_k<<<dim3(2, 32, 2), 256, 0, stream>>>(
      yhp16, 1024, DSU, outw16, 1024, 262144L, ws + F_YF, 256, (long)SZ_T,
      4096, 256, 1024, 0, 0);
  // final proj with fused r-build
  gemm_r_k<<<dim3(2, 32, 1), 256, 0, stream>>>(ws + F_YF, ws + F_YB, ws + F_T, projw16, pr);
  // out = x + pr^T + proj_b
  final_add2_k<<<dim3(64, 8, 2), 256, 0, stream>>>(x, pr, proj_b, out);
}